// Round 8
// baseline (448.392 us; speedup 1.0000x reference)
//
#include <hip/hip_runtime.h>

#define KB 8
#define KN 4096
#define KNA 64
#define KH 12
#define KD 32
#define KC 384
#define KC2 768
#define KSCALE 0.17677669529663688f

typedef __bf16 bf16x8 __attribute__((ext_vector_type(8)));
typedef float  f32x4  __attribute__((ext_vector_type(4)));

static __device__ __forceinline__ unsigned short f2bf(float f) {
    unsigned int u = __builtin_bit_cast(unsigned int, f);
    u += 0x7FFFu + ((u >> 16) & 1u);
    return (unsigned short)(u >> 16);
}

static __device__ __forceinline__ void gld_lds16(const unsigned short* g, unsigned short* l) {
    __builtin_amdgcn_global_load_lds(
        (const __attribute__((address_space(1))) unsigned int*)g,
        (__attribute__((address_space(3))) unsigned int*)l, 16, 0, 0);
}

#define MFMA_16x16x32 __builtin_amdgcn_mfma_f32_16x16x32_bf16

// ---------------- K0: Kag = agent@Wk_ag + bk ; Qa = agent@Wq_ag + bq
__global__ __launch_bounds__(256) void k_agent_proj(
    const float* __restrict__ agent,
    const float* __restrict__ Wk_ag, const float* __restrict__ bk_ag,
    const float* __restrict__ Wq_ag, const float* __restrict__ bq_ag,
    float* __restrict__ Kag, float* __restrict__ Qa)
{
    __shared__ float a_lds[8][KC];
    const int tid = threadIdx.x;
    const int rg  = blockIdx.x;
    const float* W    = blockIdx.y ? Wq_ag : Wk_ag;
    const float* bias = blockIdx.y ? bq_ag : bk_ag;
    float* dst        = blockIdx.y ? Qa    : Kag;

    const float4* src4 = reinterpret_cast<const float4*>(agent) + (size_t)rg * 768;
    float4* al4 = reinterpret_cast<float4*>(&a_lds[0][0]);
    #pragma unroll
    for (int l = 0; l < 3; ++l) al4[tid + l*256] = src4[tid + l*256];
    __syncthreads();

    float acc[8][3] = {};
    for (int c = 0; c < KC; ++c) {
        float w0 = W[(size_t)c*KC2 + tid];
        float w1 = W[(size_t)c*KC2 + tid + 256];
        float w2 = W[(size_t)c*KC2 + tid + 512];
        #pragma unroll
        for (int r = 0; r < 8; ++r) {
            float a = a_lds[r][c];
            acc[r][0] = fmaf(a, w0, acc[r][0]);
            acc[r][1] = fmaf(a, w1, acc[r][1]);
            acc[r][2] = fmaf(a, w2, acc[r][2]);
        }
    }
    float b0 = bias[tid], b1 = bias[tid+256], b2 = bias[tid+512];
    #pragma unroll
    for (int r = 0; r < 8; ++r) {
        size_t base = (size_t)(rg*8 + r) * KC2;
        dst[base + tid      ] = acc[r][0] + b0;
        dst[base + tid + 256] = acc[r][1] + b1;
        dst[base + tid + 512] = acc[r][2] + b2;
    }
}

// ---------------- transpose Wk_hf [384,768] -> WkT [768,384] (f32)
__global__ __launch_bounds__(256) void k_transpose(
    const float* __restrict__ Win, float* __restrict__ Wout)
{
    __shared__ float tile[32][33];
    const int tx = threadIdx.x, ty = threadIdx.y;
    const int j0 = blockIdx.x * 32, c0 = blockIdx.y * 32;
    #pragma unroll
    for (int yy = 0; yy < 4; ++yy)
        tile[ty + yy*8][tx] = Win[(size_t)(c0 + ty + yy*8)*KC2 + j0 + tx];
    __syncthreads();
    #pragma unroll
    for (int yy = 0; yy < 4; ++yy)
        Wout[(size_t)(j0 + ty + yy*8)*KC + c0 + tx] = tile[tx][ty + yy*8];
}

// ---------------- tcastT: src f32 [R][C] -> dstT bf16 frag-major [(r>>5)][C][32]
//                  optional dstRM: bf16 row-major, 16B-granule XOR-swizzled (g^(r&7))
__global__ __launch_bounds__(256) void k_tcastT(
    const float* __restrict__ src, unsigned short* __restrict__ dstT,
    unsigned short* __restrict__ dstRM,
    int R, int C, long sstride, long dTstride, long dRMstride)
{
    __shared__ unsigned short lds[64][80];
    const int t = threadIdx.x;
    const int r0 = blockIdx.x * 64, c0 = blockIdx.y * 64;
    const float* s = src + (size_t)blockIdx.z * sstride;
    #pragma unroll
    for (int i = 0; i < 16; ++i) {
        int f = t + i*256; int rr = f >> 6, cc = f & 63;
        lds[rr][cc] = f2bf(s[(size_t)(r0+rr)*C + c0 + cc]);
    }
    __syncthreads();
    if (dstT) {
        unsigned short* dT = dstT + (size_t)blockIdx.z * dTstride;
        #pragma unroll
        for (int i = 0; i < 8; ++i) {
            int o = t + i*256;
            int chunk = o >> 10, c = (o >> 4) & 63, pair = o & 15;
            int r = chunk*32 + pair*2;
            unsigned int v = (unsigned int)lds[r][c] | ((unsigned int)lds[r+1][c] << 16);
            size_t off = ((size_t)((r0>>5) + chunk)*C + c0 + c)*32 + pair*2;
            *reinterpret_cast<unsigned int*>(dT + off) = v;
        }
    }
    if (dstRM) {
        unsigned short* dR = dstRM + (size_t)blockIdx.z * dRMstride;
        #pragma unroll
        for (int i = 0; i < 2; ++i) {
            int idx = t*2 + i;
            int n = idx >> 3, gt = idx & 7;
            int g = (c0 >> 3) + gt;
            int slot = g ^ ((r0 + n) & 7);
            *reinterpret_cast<bf16x8*>(dR + (size_t)(r0+n)*C + slot*8) =
                *reinterpret_cast<const bf16x8*>(&lds[n][gt*8]);
        }
    }
}

// ---------------- K1: E[b][c][hm]  (f32)
__global__ __launch_bounds__(256) void k_build_E(
    const float* __restrict__ Wq_lf, const float* __restrict__ Kag,
    const float* __restrict__ wa, float* __restrict__ E)
{
    __shared__ float w_lds[8][KC2];
    const int tid = threadIdx.x;
    const int cg = blockIdx.x;
    const int b  = blockIdx.y;
    const float4* src = reinterpret_cast<const float4*>(Wq_lf + (size_t)cg*8*KC2);
    float4* dst4 = reinterpret_cast<float4*>(&w_lds[0][0]);
    #pragma unroll
    for (int l = 0; l < 6; ++l) dst4[tid + l*256] = src[tid + l*256];
    __syncthreads();
    const float s0 = KSCALE * wa[0], s1 = KSCALE * wa[1];
    float acc[8][3] = {};
    #pragma unroll
    for (int j = 0; j < 3; ++j) {
        const int hm = tid + j*256;
        const int h = hm >> 6, m = hm & 63;
        const float* kp = Kag + (size_t)(b*KNA + m)*KC2;
        const int base1 = h*KD, base2 = KC + h*KD;
        for (int d = 0; d < KD; ++d) {
            float a1 = kp[base1 + d] * s0;
            float a2 = kp[base2 + d] * s1;
            #pragma unroll
            for (int cr = 0; cr < 8; ++cr)
                acc[cr][j] += w_lds[cr][base1+d]*a1 + w_lds[cr][base2+d]*a2;
        }
    }
    #pragma unroll
    for (int cr = 0; cr < 8; ++cr)
        #pragma unroll
        for (int j = 0; j < 3; ++j)
            E[((size_t)b*KC + cg*8 + cr)*KC2 + tid + j*256] = acc[cr][j];
}

// ---------------- K2b: F_bf[b][hm][c] bf16 row-major
__global__ __launch_bounds__(128) void k_build_F(
    const float* __restrict__ WkT, const float* __restrict__ Qa,
    const float* __restrict__ wb, unsigned short* __restrict__ Fbf)
{
    __shared__ float q_lds[8][64];
    const int tid = threadIdx.x;
    const int g = blockIdx.x;
    const int b = blockIdx.y;
    const int h = (g*8) >> 6;
    const float t0 = KSCALE*wb[0], t1 = KSCALE*wb[1];
    #pragma unroll
    for (int l = 0; l < 4; ++l) {
        int v = tid + l*128;
        int i = v >> 6, d = v & 63;
        int m = (g*8 + i) & 63;
        int jj   = (d < KD) ? (h*KD + d) : (KC + h*KD + d - KD);
        float cf = (d < KD) ? t0 : t1;
        q_lds[i][d] = cf * Qa[(size_t)(b*KNA + m)*KC2 + jj];
    }
    __syncthreads();
    float acc[8][3] = {};
    for (int d = 0; d < 64; ++d) {
        int row = (d < KD) ? (h*KD + d) : (KC + h*KD + d - KD);
        const float* wr = WkT + (size_t)row*KC;
        float w0 = wr[tid], w1 = wr[tid+128], w2 = wr[tid+256];
        #pragma unroll
        for (int i = 0; i < 8; ++i) {
            float q = q_lds[i][d];
            acc[i][0] = fmaf(q, w0, acc[i][0]);
            acc[i][1] = fmaf(q, w1, acc[i][1]);
            acc[i][2] = fmaf(q, w2, acc[i][2]);
        }
    }
    #pragma unroll
    for (int i = 0; i < 8; ++i)
        #pragma unroll
        for (int l = 0; l < 3; ++l)
            Fbf[((size_t)b*KC2 + g*8 + i)*KC + tid + l*128] = f2bf(acc[i][l]);
}

// ---------------- K1c: bias constants cA, cB
__global__ __launch_bounds__(256) void k_build_c(
    const float* __restrict__ bq_lf, const float* __restrict__ Kag,
    const float* __restrict__ wa, const float* __restrict__ ba,
    const float* __restrict__ bk_hf, const float* __restrict__ Qa,
    const float* __restrict__ wb, const float* __restrict__ bbv,
    float* __restrict__ cA, float* __restrict__ cB)
{
    const int b = blockIdx.x;
    const float s0 = KSCALE*wa[0], s1 = KSCALE*wa[1];
    const float t0 = KSCALE*wb[0], t1 = KSCALE*wb[1];
    for (int hm = threadIdx.x; hm < KC2; hm += 256) {
        int h = hm >> 6, m = hm & 63;
        const float* kp = Kag + (size_t)(b*KNA + m)*KC2;
        const float* qp = Qa  + (size_t)(b*KNA + m)*KC2;
        float a = 0.f, bb2 = 0.f;
        for (int d = 0; d < KD; ++d) {
            a   += s0*bq_lf[h*KD+d]*kp[h*KD+d] + s1*bq_lf[KC+h*KD+d]*kp[KC+h*KD+d];
            bb2 += t0*bk_hf[h*KD+d]*qp[h*KD+d] + t1*bk_hf[KC+h*KD+d]*qp[KC+h*KD+d];
        }
        cA[(size_t)b*KC2 + hm] = a   + ba[0];
        cB[(size_t)b*KC2 + hm] = bb2 + bbv[0];
    }
}

// ---------------- k_vproj: V = attn @ Wv + bv -> Vt2 frag-major bf16 [b][n>>5][384][32]
__global__ __launch_bounds__(512, 4) void k_vproj(
    const unsigned short* __restrict__ Abf, const unsigned short* __restrict__ WvT2,
    const float* __restrict__ bv, unsigned short* __restrict__ Vt2)
{
    extern __shared__ char smem[];
    unsigned short* a_rm = (unsigned short*)smem;   // 49152B
    const int tid = threadIdx.x;
    const int wid = tid >> 6, lane = tid & 63;
    const int tx = lane & 15, ty = lane >> 4;
    const int nb = blockIdx.x, b = blockIdx.y;
    const int wn = wid >> 2, wd = wid & 3;

    const unsigned short* atile = Abf + ((size_t)b*KN + nb*64)*KC;
    #pragma unroll
    for (int i = 0; i < 6; ++i)
        gld_lds16(atile + (size_t)tid*8 + i*4096, a_rm + tid*8 + i*4096);

    f32x4 acc[2][6];
    #pragma unroll
    for (int i = 0; i < 2; ++i)
        #pragma unroll
        for (int j = 0; j < 6; ++j) acc[i][j] = (f32x4){0.f,0.f,0.f,0.f};
    __syncthreads();

    #pragma unroll
    for (int kk = 0; kk < 12; ++kk) {
        bf16x8 af[2];
        #pragma unroll
        for (int ns = 0; ns < 2; ++ns) {
            int n = wn*32 + ns*16 + tx;
            int gs = (kk*4 + ty) ^ (n & 7);
            af[ns] = *reinterpret_cast<const bf16x8*>(a_rm + n*384 + gs*8);
        }
        #pragma unroll
        for (int cs = 0; cs < 6; ++cs) {
            int d = wd*96 + cs*16 + tx;
            bf16x8 bf = *reinterpret_cast<const bf16x8*>(WvT2 + ((size_t)kk*KC + d)*32 + ty*8);
            #pragma unroll
            for (int ns = 0; ns < 2; ++ns)
                acc[ns][cs] = MFMA_16x16x32(af[ns], bf, acc[ns][cs], 0, 0, 0);
        }
    }
    // epilogue: + bv, write frag-major bf16
    #pragma unroll
    for (int cs = 0; cs < 6; ++cs) {
        int d = wd*96 + cs*16 + tx;
        float bvv = bv[d];
        #pragma unroll
        for (int ns = 0; ns < 2; ++ns) {
            ushort4 h4;
            h4.x = f2bf(acc[ns][cs][0] + bvv);
            h4.y = f2bf(acc[ns][cs][1] + bvv);
            h4.z = f2bf(acc[ns][cs][2] + bvv);
            h4.w = f2bf(acc[ns][cs][3] + bvv);
            size_t off = (((size_t)b*(KN>>5) + nb*2 + wn)*KC + d)*32 + ns*16 + ty*4;
            *reinterpret_cast<ushort4*>(Vt2 + off) = h4;
        }
    }
}

// ---------------- K3: V-form MFMA flash (branch B), 64-row tiles (round-6 config)
// LDS: a_rm 49152 + p [64][72] bf16 9216 + redl 512 = 58880 -> 2 blocks/CU
__global__ __launch_bounds__(512, 4) void k_flash3(
    const unsigned short* __restrict__ Abf, const unsigned short* __restrict__ Vt2,
    const unsigned short* __restrict__ Fbf, const float* __restrict__ cB,
    float* __restrict__ Vpart, float* __restrict__ lpart,
    int nchunk, int NK, int g_per)
{
    extern __shared__ char smem[];
    unsigned short* a_rm = (unsigned short*)smem;
    unsigned short* p    = (unsigned short*)(smem + 49152);
    float*          redl = (float*)(smem + 58368);

    const int tid = threadIdx.x;
    const int wid = tid >> 6, lane = tid & 63;
    const int tx = lane & 15, ty = lane >> 4;
    const unsigned bid = blockIdx.x;
    const int h = bid / g_per;
    const unsigned g = bid - h*g_per;
    const int b = g / nchunk;
    const int chunk = g - b*nchunk;
    const int n0 = chunk * NK;
    const int wn = wid >> 2, wh = wid & 3;   // QK^T roles
    const int wph = wid >> 1, wpd = wid & 1; // PV roles

    bf16x8 ffrag[12];
    {
        const unsigned short* fp = Fbf + ((size_t)(b*KC2 + h*64 + wh*16 + tx))*KC + ty*8;
        #pragma unroll
        for (int kk = 0; kk < 12; ++kk)
            ffrag[kk] = *reinterpret_cast<const bf16x8*>(fp + kk*32);
    }
    const float cbv = cB[(size_t)b*KC2 + h*64 + wh*16 + tx];
    float lacc = 0.f;
    f32x4 Vacc = (f32x4){0.f,0.f,0.f,0.f};

    const unsigned short* atile = Abf + ((size_t)b*KN + n0)*KC;
    #pragma unroll
    for (int i = 0; i < 6; ++i)
        gld_lds16(atile + (size_t)tid*8 + i*4096, a_rm + tid*8 + i*4096);
    __syncthreads();

    const int NT = NK >> 6;
    for (int nt = 0; nt < NT; ++nt) {
        // V B-frags for this tile (hidden under QK^T)
        size_t vrow = (size_t)b*(KN >> 5) + ((n0 + nt*64) >> 5);
        bf16x8 vf0 = *reinterpret_cast<const bf16x8*>(
            Vt2 + ((vrow + 0)*KC + h*KD + wpd*16 + tx)*32 + ty*8);
        bf16x8 vf1 = *reinterpret_cast<const bf16x8*>(
            Vt2 + ((vrow + 1)*KC + h*KD + wpd*16 + tx)*32 + ty*8);
        // QK^T: T'[n][hm]
        f32x4 tacc[2];
        tacc[0] = (f32x4){0.f,0.f,0.f,0.f};
        tacc[1] = (f32x4){0.f,0.f,0.f,0.f};
        __builtin_amdgcn_s_setprio(1);
        #pragma unroll
        for (int kk = 0; kk < 12; ++kk) {
            #pragma unroll
            for (int ns = 0; ns < 2; ++ns) {
                int n = wn*32 + ns*16 + tx;
                int gs = (kk*4 + ty) ^ (n & 7);
                bf16x8 af = *reinterpret_cast<const bf16x8*>(a_rm + n*384 + gs*8);
                tacc[ns] = MFMA_16x16x32(af, ffrag[kk], tacc[ns], 0, 0, 0);
            }
        }
        __builtin_amdgcn_s_setprio(0);
        // exp + lacc + pack P bf16 into p[hm][n]
        #pragma unroll
        for (int ns = 0; ns < 2; ++ns) {
            float e0 = __expf(tacc[ns][0] + cbv);
            float e1 = __expf(tacc[ns][1] + cbv);
            float e2 = __expf(tacc[ns][2] + cbv);
            float e3 = __expf(tacc[ns][3] + cbv);
            lacc += e0 + e1 + e2 + e3;
            int hm = wh*16 + tx;
            int np = wn*32 + ns*16 + ty*4;
            ushort4 h4 = { f2bf(e0), f2bf(e1), f2bf(e2), f2bf(e3) };
            *reinterpret_cast<ushort4*>(p + hm*72 + np) = h4;
        }
        __syncthreads();   // p visible; all QK^T reads of a_rm done
        if (nt + 1 < NT) {  // async stage next tile (overlaps PV)
            const unsigned short* at = atile + (size_t)(nt+1)*64*KC;
            #pragma unroll
            for (int i = 0; i < 6; ++i)
                gld_lds16(at + (size_t)tid*8 + i*4096, a_rm + tid*8 + i*4096);
        }
        // PV: Vacc += P_h @ V_h  (wave owns 16 hm x 16 d)
        bf16x8 pa0 = *reinterpret_cast<const bf16x8*>(p + (wph*16 + tx)*72 + 0*32 + ty*8);
        bf16x8 pa1 = *reinterpret_cast<const bf16x8*>(p + (wph*16 + tx)*72 + 1*32 + ty*8);
        Vacc = MFMA_16x16x32(pa0, vf0, Vacc, 0, 0, 0);
        Vacc = MFMA_16x16x32(pa1, vf1, Vacc, 0, 0, 0);
        __syncthreads();   // PV p-reads done + DMA landed
    }
    // epilogue: Vpart f32 [b][h][chunk][64 hm][32 d]
    #pragma unroll
    for (int r = 0; r < 4; ++r)
        Vpart[(((size_t)(b*KH + h)*nchunk + chunk)*64 + wph*16 + ty*4 + r)*32 + wpd*16 + tx]
            = Vacc[r];
    lacc += __shfl_xor(lacc, 16);
    lacc += __shfl_xor(lacc, 32);
    if (lane < 16) redl[wn*64 + wh*16 + tx] = lacc;
    __syncthreads();
    if (tid < 64)
        lpart[((size_t)b*KC2 + h*64 + tid)*nchunk + chunk] = redl[tid] + redl[64 + tid];
}

// ---------------- K4: combine3 (fused): x_s = (sum_ch Vpart)/l ; Mt2 = bf16 frag-major(x_s @ Wproj_h)
__global__ __launch_bounds__(384) void k_combine3(
    const float* __restrict__ Vpart, const float* __restrict__ lpart,
    const float* __restrict__ Wproj, unsigned short* __restrict__ Mt2, int nchunk)
{
    __shared__ float xs[64][32];
    __shared__ float invl[64];
    __shared__ float lred[64][4];
    const int h = blockIdx.x, b = blockIdx.y;
    const int tid = threadIdx.x;   // 384
    if (tid < 256) {
        int hm = tid >> 2, q = tid & 3;
        float s = 0.f;
        for (int ch = q; ch < nchunk; ch += 4)
            s += lpart[((size_t)b*KC2 + h*64 + hm)*nchunk + ch];
        lred[hm][q] = s;
    }
    __syncthreads();
    if (tid < 64)
        invl[tid] = 1.f / (lred[tid][0] + lred[tid][1] + lred[tid][2] + lred[tid][3]);
    __syncthreads();
    for (int v = tid; v < 2048; v += 384) {
        int hm = v >> 5;
        float u = 0.f;
        const float* vp = Vpart + ((size_t)(b*KH + h)*nchunk)*2048 + v;
        for (int ch = 0; ch < nchunk; ++ch) u += vp[(size_t)ch*2048];
        xs[hm][v & 31] = u * invl[hm];
    }
    __syncthreads();
    // GEMM: thread e computes M[m][e] for all 64 m; write Mt2 lines of 32 m
    const int e = tid;
    float wp[32];
    #pragma unroll
    for (int d = 0; d < 32; ++d) wp[d] = Wproj[(size_t)(h*KD + d)*KC + e];
    #pragma unroll
    for (int half = 0; half < 2; ++half) {
        ushort4 line[8];
        #pragma unroll
        for (int mq = 0; mq < 8; ++mq) {
            float a4[4];
            #pragma unroll
            for (int mr = 0; mr < 4; ++mr) {
                float a = 0.f;
                #pragma unroll
                for (int d = 0; d < 32; ++d)
                    a = fmaf(xs[half*32 + mq*4 + mr][d], wp[d], a);
                a4[mr] = a;
            }
            line[mq] = (ushort4){ f2bf(a4[0]), f2bf(a4[1]), f2bf(a4[2]), f2bf(a4[3]) };
        }
        unsigned short* dst = Mt2 + (((size_t)(b*KH + h)*2 + half)*KC + e)*32;
        #pragma unroll
        for (int q = 0; q < 4; ++q)
            reinterpret_cast<uint4*>(dst)[q] =
                reinterpret_cast<const uint4*>(line)[q];
    }
}

// ---------------- K5: MFMA out v5 (branch A): 64-row tiles, 2 heads/iter, SW-pipelined
// LDS: xb [64][384] bf16 swz 49152 @0; p [64][140] bf16 17920 @49152; red [2][64][4] f32 2048 @67072
// total 69120 -> 2 blocks/CU
__global__ __launch_bounds__(512, 4) void k_out3(
    const float* __restrict__ x, const unsigned short* __restrict__ Et2,
    const float* __restrict__ cA, const unsigned short* __restrict__ Mt2,
    const float* __restrict__ bproj, float* __restrict__ out)
{
    extern __shared__ char smem[];
    unsigned short* xb = (unsigned short*)smem;
    unsigned short* p  = (unsigned short*)(smem + 49152);   // pitch 140
    float* red = (float*)(smem + 67072);                    // [2][64][4]

    const int tid = threadIdx.x;
    const int wid = tid >> 6, lane = tid & 63;
    const int tx = lane & 15, ty = lane >> 4;
    const int nb = blockIdx.x, b = blockIdx.y;
    const int hq2 = wid >> 2, wm = wid & 3;   // QK^T: head-of-pair, m-slice
    const int es = wid * 48;                  // PV: e-slice

    f32x4 oacc[4][3];
    #pragma unroll
    for (int i = 0; i < 4; ++i)
        #pragma unroll
        for (int j = 0; j < 3; ++j) oacc[i][j] = (f32x4){0.f,0.f,0.f,0.f};

    {   // stage xb once (swizzled bf16 from f32 x)
        const float4* src = reinterpret_cast<const float4*>(x + ((size_t)(b*KN + nb*64))*KC);
        #pragma unroll
        for (int i = 0; i < 12; ++i) {
            int f = tid + i*512;
            int n = f / 96, c4 = f % 96;
            float4 v = src[f];
            ushort4 h4 = { f2bf(v.x), f2bf(v.y), f2bf(v.z), f2bf(v.w) };
            int g = c4 >> 1, half = c4 & 1;
            int gs = g ^ (n & 7);
            *reinterpret_cast<ushort4*>(xb + n*384 + gs*8 + half*4) = h4;
        }
    }
    __syncthreads();

    // prologue: QK^T(it=0) for head hq2
    f32x4 tacc[4];
    float cav = cA[(size_t)b*KC2 + hq2*64 + wm*16 + tx];
    #pragma unroll
    for (int ng = 0; ng < 4; ++ng) tacc[ng] = (f32x4){0.f,0.f,0.f,0.f};
    #pragma unroll
    for (int kk = 0; kk < 12; ++kk) {
        bf16x8 ef = *reinterpret_cast<const bf16x8*>(
            Et2 + (((size_t)b*12 + kk)*KC2 + hq2*64 + wm*16 + tx)*32 + ty*8);
        #pragma unroll
        for (int ng = 0; ng < 4; ++ng) {
            int n = ng*16 + tx;
            int gs = (kk*4 + ty) ^ (n & 7);
            bf16x8 af = *reinterpret_cast<const bf16x8*>(xb + n*384 + gs*8);
            tacc[ng] = MFMA_16x16x32(af, ef, tacc[ng], 0, 0, 0);
        }
    }

    for (int it = 0; it < 6; ++it) {
        // ---- SM(it): exp + partial row-sum over this wave's 16 m
        float s[4][4];
        #pragma unroll
        for (int ng = 0; ng < 4; ++ng)
            #pragma unroll
            for (int r = 0; r < 4; ++r) {
                tacc[ng][r] = __expf(tacc[ng][r] + cav);
                s[ng][r] = tacc[ng][r];
            }
        #pragma unroll
        for (int mask = 1; mask < 16; mask <<= 1)
            #pragma unroll
            for (int ng = 0; ng < 4; ++ng)
                #pragma unroll
                for (int r = 0; r < 4; ++r)
                    s[ng][r] += __shfl_xor(s[ng][r], mask);
        if (tx == 0) {
            #pragma unroll
            for (int ng = 0; ng < 4; ++ng)
                #pragma unroll
                for (int r = 0; r < 4; ++r)
                    red[(hq2*64 + ng*16 + ty*4 + r)*4 + wm] = s[ng][r];
        }
        __syncthreads();   // barA: red visible; PV(it-1) p-reads complete
        // ---- normalize + write P bf16 into p[n][hq2*64 + wm*16 + tx]
        #pragma unroll
        for (int ng = 0; ng < 4; ++ng)
            #pragma unroll
            for (int r = 0; r < 4; ++r) {
                int n = ng*16 + ty*4 + r;
                float4 rv = *reinterpret_cast<const float4*>(red + (hq2*64 + n)*4);
                float inv = 1.f / (rv.x + rv.y + rv.z + rv.w);
                p[n*140 + hq2*64 + wm*16 + tx] = f2bf(tacc[ng][r] * inv);
            }
        __syncthreads();   // barB: p visible
        // ---- barrier-free region: QK^T(it+1) + PV(it) — 48 MFMA, co-scheduled
        __builtin_amdgcn_s_setprio(1);
        if (it < 5) {
            const int hq = (it+1)*2 + hq2;
            cav = cA[(size_t)b*KC2 + hq*64 + wm*16 + tx];
            #pragma unroll
            for (int ng = 0; ng < 4; ++ng) tacc[ng] = (f32x4){0.f,0.f,0.f,0.f};
            #pragma unroll
            for (int kk = 0; kk < 12; ++kk) {
                bf16x8 ef = *reinterpret_cast<const bf16x8*>(
                    Et2 + (((size_t)b*12 + kk)*KC2 + hq*64 + wm*16 + tx)*32 + ty*8);
                #pragma unroll
                for (int ng = 0; ng < 4; ++ng) {
                    int n = ng*16 + tx;
                    int gs = (kk*4 + ty) ^ (n & 7);
                    bf16x8 af = *reinterpret_cast<const bf16x8*>(xb + n*384 + gs*8);
                    tacc[ng] = MFMA_16x16x32(af, ef, tacc[ng], 0, 0, 0);
                }
            }
        }
        // PV(it): oacc += P[64 n][128 k] @ M2[128 k][48 e-slice]
        #pragma unroll
        for (int ks = 0; ks < 4; ++ks) {
            const int hM = it*2 + (ks >> 1);
            const int inner = ks & 1;
            bf16x8 pa[4];
            #pragma unroll
            for (int ng = 0; ng < 4; ++ng)
                pa[ng] = *reinterpret_cast<const bf16x8*>(
                    p + (ng*16 + tx)*140 + ks*32 + ty*8);
            #pragma unroll
            for (int j = 0; j < 3; ++j) {
                bf16x8 mf = *reinterpret_cast<const bf16x8*>(
                    Mt2 + (((size_t)(b*KH + hM)*2 + inner)*KC + es + j*16 + tx)*32 + ty*8);
                #pragma unroll
                for (int ng = 0; ng < 4; ++ng)
                    oacc[ng][j] = MFMA_16x16x32(pa[ng], mf, oacc[ng][j], 0, 0, 0);
            }
        }
        __builtin_amdgcn_s_setprio(0);
    }
    // epilogue
    float bp[3];
    #pragma unroll
    for (int j = 0; j < 3; ++j) bp[j] = bproj[es + j*16 + tx];
    #pragma unroll
    for (int ng = 0; ng < 4; ++ng)
        #pragma unroll
        for (int r = 0; r < 4; ++r) {
            size_t base = (size_t)(b*KN + nb*64 + ng*16 + ty*4 + r)*KC;
            #pragma unroll
            for (int j = 0; j < 3; ++j)
                out[base + es + j*16 + tx] = oacc[ng][j][r] + bp[j];
        }
}

extern "C" void kernel_launch(void* const* d_in, const int* in_sizes, int n_in,
                              void* d_out, int out_size, void* d_ws, size_t ws_size,
                              hipStream_t stream) {
    const float* x     = (const float*)d_in[0];
    const float* attn  = (const float*)d_in[1];
    const float* agent = (const float*)d_in[2];
    const float* Wq_lf = (const float*)d_in[3];
    const float* bq_lf = (const float*)d_in[4];
    const float* Wk_ag = (const float*)d_in[5];
    const float* bk_ag = (const float*)d_in[6];
    const float* wa    = (const float*)d_in[7];
    const float* ba    = (const float*)d_in[8];
    const float* Wq_ag = (const float*)d_in[9];
    const float* bq_ag = (const float*)d_in[10];
    const float* Wk_hf = (const float*)d_in[11];
    const float* bk_hf = (const float*)d_in[12];
    const float* Wv_hf = (const float*)d_in[13];
    const float* bv_hf = (const float*)d_in[14];
    const float* wb    = (const float*)d_in[15];
    const float* bb    = (const float*)d_in[16];
    const float* Wproj = (const float*)d_in[17];
    const float* bproj = (const float*)d_in[18];
    float* out = (float*)d_out;
    float* ws  = (float*)d_ws;

    // workspace layout (f32 units)
    const size_t o_Kag  = 0;          // 393216
    const size_t o_Qa   = 393216;     // 393216
    const size_t o_E    = 786432;     // 2359296
    const size_t o_cA   = 3145728;    // 6144
    const size_t o_cB   = 3151872;    // 6144
    const size_t o_Fbf  = 3158016;    // 1179648
    const size_t o_WkT  = 6696960;    // 294912
    const size_t o_Et2  = 6991872;    // 1179648
    const size_t o_Mt2  = 8171520;    // 1179648
    const size_t o_WvT2 = 9351168;    // 73728
    const size_t o_Abf  = 9424896;    // 3145728
    const size_t o_Vt2  = 12570624;   // 6291456
    const size_t o_lp_base = 18862080;

    int nchunk = 8;
    {
        const int cands[3] = {32, 16, 8};
        for (int ci = 0; ci < 3; ++ci) {
            size_t need = (o_lp_base + (size_t)202752 * cands[ci]) * 4ull;
            if (need <= ws_size) { nchunk = cands[ci]; break; }
        }
    }
    const size_t o_lp = o_lp_base;
    const size_t o_Vp = o_lp + (size_t)6144 * nchunk;

    unsigned short* Fbf  = (unsigned short*)(ws + o_Fbf);
    unsigned short* Et2  = (unsigned short*)(ws + o_Et2);
    unsigned short* Mt2  = (unsigned short*)(ws + o_Mt2);
    unsigned short* WvT2 = (unsigned short*)(ws + o_WvT2);
    unsigned short* Abf  = (unsigned short*)(ws + o_Abf);
    unsigned short* Vt2  = (unsigned short*)(ws + o_Vt2);

    k_agent_proj<<<dim3(64, 2), 256, 0, stream>>>(agent, Wk_ag, bk_ag, Wq_ag, bq_ag,
                                                  ws + o_Kag, ws + o_Qa);
    k_transpose<<<dim3(24, 12), dim3(32, 8), 0, stream>>>(Wk_hf, ws + o_WkT);
    k_build_E<<<dim3(48, 8), 256, 0, stream>>>(Wq_lf, ws + o_Kag, wa, ws + o_E);
    k_tcastT<<<dim3(6, 12, 8), 256, 0, stream>>>(ws + o_E, Et2, nullptr,
                                                 KC, KC2, (long)KC*KC2, (long)KC*KC2, 0);
    k_build_F<<<dim3(96, 8), 128, 0, stream>>>(ws + o_WkT, ws + o_Qa, wb, Fbf);
    k_build_c<<<8, 256, 0, stream>>>(bq_lf, ws + o_Kag, wa, ba, bk_hf, ws + o_Qa,
                                     wb, bb, ws + o_cA, ws + o_cB);
    // attn -> Abf (swizzled row-major bf16)
    k_tcastT<<<dim3(64, 6, 8), 256, 0, stream>>>(attn, nullptr, Abf,
                                                 KN, KC, (long)KN*KC, 0, (long)KN*KC);
    // Wv [384][384] -> WvT2 frag-major
    k_tcastT<<<dim3(6, 6, 1), 256, 0, stream>>>(Wv_hf, WvT2, nullptr,
                                                 KC, KC, 0, 0, 0);

    const int vp_lds = 49152;
    const int fl_lds = 58880;
    const int ko_lds = 69120;
    (void)hipFuncSetAttribute(reinterpret_cast<const void*>(k_vproj),
                              hipFuncAttributeMaxDynamicSharedMemorySize, vp_lds);
    (void)hipFuncSetAttribute(reinterpret_cast<const void*>(k_flash3),
                              hipFuncAttributeMaxDynamicSharedMemorySize, fl_lds);
    (void)hipFuncSetAttribute(reinterpret_cast<const void*>(k_out3),
                              hipFuncAttributeMaxDynamicSharedMemorySize, ko_lds);

    k_vproj<<<dim3(KN/64, KB), 512, vp_lds, stream>>>(Abf, WvT2, bv_hf, Vt2);

    const int g_per = KB * nchunk;
    k_flash3<<<dim3(KH * g_per), 512, fl_lds, stream>>>(
        Abf, Vt2, Fbf, ws + o_cB, ws + o_Vp, ws + o_lp, nchunk, KN / nchunk, g_per);
    k_combine3<<<dim3(KH, KB), 384, 0, stream>>>(
        ws + o_Vp, ws + o_lp, Wproj, Mt2, nchunk);
    k_out3<<<dim3(KN/64, KB), 512, ko_lds, stream>>>(
        x, Et2, ws + o_cA, Mt2, bproj, out);
}

// Round 9
// 392.026 us; speedup vs baseline: 1.1438x; 1.1438x over previous
//
#include <hip/hip_runtime.h>

#define KB 8
#define KN 4096
#define KNA 64
#define KH 12
#define KD 32
#define KC 384
#define KC2 768
#define KSCALE 0.17677669529663688f

typedef __bf16 bf16x8 __attribute__((ext_vector_type(8)));
typedef float  f32x4  __attribute__((ext_vector_type(4)));

static __device__ __forceinline__ unsigned short f2bf(float f) {
    unsigned int u = __builtin_bit_cast(unsigned int, f);
    u += 0x7FFFu + ((u >> 16) & 1u);
    return (unsigned short)(u >> 16);
}

static __device__ __forceinline__ void gld_lds16(const unsigned short* g, unsigned short* l) {
    __builtin_amdgcn_global_load_lds(
        (const __attribute__((address_space(1))) unsigned int*)g,
        (__attribute__((address_space(3))) unsigned int*)l, 16, 0, 0);
}

#define MFMA_16x16x32 __builtin_amdgcn_mfma_f32_16x16x32_bf16

// ---------------- K0: Kag = agent@Wk_ag + bk ; Qa = agent@Wq_ag + bq
__global__ __launch_bounds__(256) void k_agent_proj(
    const float* __restrict__ agent,
    const float* __restrict__ Wk_ag, const float* __restrict__ bk_ag,
    const float* __restrict__ Wq_ag, const float* __restrict__ bq_ag,
    float* __restrict__ Kag, float* __restrict__ Qa)
{
    __shared__ float a_lds[8][KC];
    const int tid = threadIdx.x;
    const int rg  = blockIdx.x;
    const float* W    = blockIdx.y ? Wq_ag : Wk_ag;
    const float* bias = blockIdx.y ? bq_ag : bk_ag;
    float* dst        = blockIdx.y ? Qa    : Kag;

    const float4* src4 = reinterpret_cast<const float4*>(agent) + (size_t)rg * 768;
    float4* al4 = reinterpret_cast<float4*>(&a_lds[0][0]);
    #pragma unroll
    for (int l = 0; l < 3; ++l) al4[tid + l*256] = src4[tid + l*256];
    __syncthreads();

    float acc[8][3] = {};
    for (int c = 0; c < KC; ++c) {
        float w0 = W[(size_t)c*KC2 + tid];
        float w1 = W[(size_t)c*KC2 + tid + 256];
        float w2 = W[(size_t)c*KC2 + tid + 512];
        #pragma unroll
        for (int r = 0; r < 8; ++r) {
            float a = a_lds[r][c];
            acc[r][0] = fmaf(a, w0, acc[r][0]);
            acc[r][1] = fmaf(a, w1, acc[r][1]);
            acc[r][2] = fmaf(a, w2, acc[r][2]);
        }
    }
    float b0 = bias[tid], b1 = bias[tid+256], b2 = bias[tid+512];
    #pragma unroll
    for (int r = 0; r < 8; ++r) {
        size_t base = (size_t)(rg*8 + r) * KC2;
        dst[base + tid      ] = acc[r][0] + b0;
        dst[base + tid + 256] = acc[r][1] + b1;
        dst[base + tid + 512] = acc[r][2] + b2;
    }
}

// ---------------- transpose Wk_hf [384,768] -> WkT [768,384] (f32)
__global__ __launch_bounds__(256) void k_transpose(
    const float* __restrict__ Win, float* __restrict__ Wout)
{
    __shared__ float tile[32][33];
    const int tx = threadIdx.x, ty = threadIdx.y;
    const int j0 = blockIdx.x * 32, c0 = blockIdx.y * 32;
    #pragma unroll
    for (int yy = 0; yy < 4; ++yy)
        tile[ty + yy*8][tx] = Win[(size_t)(c0 + ty + yy*8)*KC2 + j0 + tx];
    __syncthreads();
    #pragma unroll
    for (int yy = 0; yy < 4; ++yy)
        Wout[(size_t)(j0 + ty + yy*8)*KC + c0 + tx] = tile[tx][ty + yy*8];
}

// ---------------- tcastT: src f32 [R][C] -> dstT bf16 frag-major [(r>>5)][C][32]
//                  optional dstRM: bf16 row-major, 16B-granule XOR-swizzled (g^(r&7))
__global__ __launch_bounds__(256) void k_tcastT(
    const float* __restrict__ src, unsigned short* __restrict__ dstT,
    unsigned short* __restrict__ dstRM,
    int R, int C, long sstride, long dTstride, long dRMstride)
{
    __shared__ unsigned short lds[64][80];
    const int t = threadIdx.x;
    const int r0 = blockIdx.x * 64, c0 = blockIdx.y * 64;
    const float* s = src + (size_t)blockIdx.z * sstride;
    #pragma unroll
    for (int i = 0; i < 16; ++i) {
        int f = t + i*256; int rr = f >> 6, cc = f & 63;
        lds[rr][cc] = f2bf(s[(size_t)(r0+rr)*C + c0 + cc]);
    }
    __syncthreads();
    if (dstT) {
        unsigned short* dT = dstT + (size_t)blockIdx.z * dTstride;
        #pragma unroll
        for (int i = 0; i < 8; ++i) {
            int o = t + i*256;
            int chunk = o >> 10, c = (o >> 4) & 63, pair = o & 15;
            int r = chunk*32 + pair*2;
            unsigned int v = (unsigned int)lds[r][c] | ((unsigned int)lds[r+1][c] << 16);
            size_t off = ((size_t)((r0>>5) + chunk)*C + c0 + c)*32 + pair*2;
            *reinterpret_cast<unsigned int*>(dT + off) = v;
        }
    }
    if (dstRM) {
        unsigned short* dR = dstRM + (size_t)blockIdx.z * dRMstride;
        #pragma unroll
        for (int i = 0; i < 2; ++i) {
            int idx = t*2 + i;
            int n = idx >> 3, gt = idx & 7;
            int g = (c0 >> 3) + gt;
            int slot = g ^ ((r0 + n) & 7);
            *reinterpret_cast<bf16x8*>(dR + (size_t)(r0+n)*C + slot*8) =
                *reinterpret_cast<const bf16x8*>(&lds[n][gt*8]);
        }
    }
}

// ---------------- K2b: F_bf[b][hm][c] bf16 row-major (branch-B scores, unchanged)
__global__ __launch_bounds__(128) void k_build_F(
    const float* __restrict__ WkT, const float* __restrict__ Qa,
    const float* __restrict__ wb, unsigned short* __restrict__ Fbf)
{
    __shared__ float q_lds[8][64];
    const int tid = threadIdx.x;
    const int g = blockIdx.x;
    const int b = blockIdx.y;
    const int h = (g*8) >> 6;
    const float t0 = KSCALE*wb[0], t1 = KSCALE*wb[1];
    #pragma unroll
    for (int l = 0; l < 4; ++l) {
        int v = tid + l*128;
        int i = v >> 6, d = v & 63;
        int m = (g*8 + i) & 63;
        int jj   = (d < KD) ? (h*KD + d) : (KC + h*KD + d - KD);
        float cf = (d < KD) ? t0 : t1;
        q_lds[i][d] = cf * Qa[(size_t)(b*KNA + m)*KC2 + jj];
    }
    __syncthreads();
    float acc[8][3] = {};
    for (int d = 0; d < 64; ++d) {
        int row = (d < KD) ? (h*KD + d) : (KC + h*KD + d - KD);
        const float* wr = WkT + (size_t)row*KC;
        float w0 = wr[tid], w1 = wr[tid+128], w2 = wr[tid+256];
        #pragma unroll
        for (int i = 0; i < 8; ++i) {
            float q = q_lds[i][d];
            acc[i][0] = fmaf(q, w0, acc[i][0]);
            acc[i][1] = fmaf(q, w1, acc[i][1]);
            acc[i][2] = fmaf(q, w2, acc[i][2]);
        }
    }
    #pragma unroll
    for (int i = 0; i < 8; ++i)
        #pragma unroll
        for (int l = 0; l < 3; ++l)
            Fbf[((size_t)b*KC2 + g*8 + i)*KC + tid + l*128] = f2bf(acc[i][l]);
}

// ---------------- K1c: bias constants cB (cA kept but unused)
__global__ __launch_bounds__(256) void k_build_c(
    const float* __restrict__ bq_lf, const float* __restrict__ Kag,
    const float* __restrict__ wa, const float* __restrict__ ba,
    const float* __restrict__ bk_hf, const float* __restrict__ Qa,
    const float* __restrict__ wb, const float* __restrict__ bbv,
    float* __restrict__ cA, float* __restrict__ cB)
{
    const int b = blockIdx.x;
    const float s0 = KSCALE*wa[0], s1 = KSCALE*wa[1];
    const float t0 = KSCALE*wb[0], t1 = KSCALE*wb[1];
    for (int hm = threadIdx.x; hm < KC2; hm += 256) {
        int h = hm >> 6, m = hm & 63;
        const float* kp = Kag + (size_t)(b*KNA + m)*KC2;
        const float* qp = Qa  + (size_t)(b*KNA + m)*KC2;
        float a = 0.f, bb2 = 0.f;
        for (int d = 0; d < KD; ++d) {
            a   += s0*bq_lf[h*KD+d]*kp[h*KD+d] + s1*bq_lf[KC+h*KD+d]*kp[KC+h*KD+d];
            bb2 += t0*bk_hf[h*KD+d]*qp[h*KD+d] + t1*bk_hf[KC+h*KD+d]*qp[KC+h*KD+d];
        }
        cA[(size_t)b*KC2 + hm] = a   + ba[0];
        cB[(size_t)b*KC2 + hm] = bb2 + bbv[0];
    }
}

// ---------------- k_kabuild: KA[b][w=br*12+h][m][k] = KSCALE*wa[br] * Kag[b][m][w*32+k] (bf16)
__global__ __launch_bounds__(256) void k_kabuild(
    const float* __restrict__ Kag, const float* __restrict__ wa,
    unsigned short* __restrict__ KA)
{
    const int b = blockIdx.x, tid = threadIdx.x;
    const float s0 = KSCALE * wa[0], s1 = KSCALE * wa[1];
    #pragma unroll
    for (int i = 0; i < 24; ++i) {
        int v = tid + i*256;                 // 6144 vec8 groups per b
        int w = v >> 8, m = (v >> 2) & 63, k8 = v & 3;
        float sc = (w >= 12) ? s1 : s0;
        const float* sp = Kag + ((size_t)(b*KNA + m))*KC2 + w*32 + k8*8;
        float4 f0 = *reinterpret_cast<const float4*>(sp);
        float4 f1 = *reinterpret_cast<const float4*>(sp + 4);
        ushort4 h0 = { f2bf(f0.x*sc), f2bf(f0.y*sc), f2bf(f0.z*sc), f2bf(f0.w*sc) };
        ushort4 h1 = { f2bf(f1.x*sc), f2bf(f1.y*sc), f2bf(f1.z*sc), f2bf(f1.w*sc) };
        unsigned short* dp = KA + ((size_t)(b*24 + w)*64 + m)*32 + k8*8;
        *reinterpret_cast<ushort4*>(dp)     = h0;
        *reinterpret_cast<ushort4*>(dp + 4) = h1;
    }
}

// ---------------- k_vproj: V = attn @ Wv + bv -> Vt2 frag-major bf16 [b][n>>5][384][32]
__global__ __launch_bounds__(512, 4) void k_vproj(
    const unsigned short* __restrict__ Abf, const unsigned short* __restrict__ WvT2,
    const float* __restrict__ bv, unsigned short* __restrict__ Vt2)
{
    extern __shared__ char smem[];
    unsigned short* a_rm = (unsigned short*)smem;   // 49152B
    const int tid = threadIdx.x;
    const int wid = tid >> 6, lane = tid & 63;
    const int tx = lane & 15, ty = lane >> 4;
    const int nb = blockIdx.x, b = blockIdx.y;
    const int wn = wid >> 2, wd = wid & 3;

    const unsigned short* atile = Abf + ((size_t)b*KN + nb*64)*KC;
    #pragma unroll
    for (int i = 0; i < 6; ++i)
        gld_lds16(atile + (size_t)tid*8 + i*4096, a_rm + tid*8 + i*4096);

    f32x4 acc[2][6];
    #pragma unroll
    for (int i = 0; i < 2; ++i)
        #pragma unroll
        for (int j = 0; j < 6; ++j) acc[i][j] = (f32x4){0.f,0.f,0.f,0.f};
    __syncthreads();

    #pragma unroll
    for (int kk = 0; kk < 12; ++kk) {
        bf16x8 af[2];
        #pragma unroll
        for (int ns = 0; ns < 2; ++ns) {
            int n = wn*32 + ns*16 + tx;
            int gs = (kk*4 + ty) ^ (n & 7);
            af[ns] = *reinterpret_cast<const bf16x8*>(a_rm + n*384 + gs*8);
        }
        #pragma unroll
        for (int cs = 0; cs < 6; ++cs) {
            int d = wd*96 + cs*16 + tx;
            bf16x8 bf = *reinterpret_cast<const bf16x8*>(WvT2 + ((size_t)kk*KC + d)*32 + ty*8);
            #pragma unroll
            for (int ns = 0; ns < 2; ++ns)
                acc[ns][cs] = MFMA_16x16x32(af[ns], bf, acc[ns][cs], 0, 0, 0);
        }
    }
    #pragma unroll
    for (int cs = 0; cs < 6; ++cs) {
        int d = wd*96 + cs*16 + tx;
        float bvv = bv[d];
        #pragma unroll
        for (int ns = 0; ns < 2; ++ns) {
            ushort4 h4;
            h4.x = f2bf(acc[ns][cs][0] + bvv);
            h4.y = f2bf(acc[ns][cs][1] + bvv);
            h4.z = f2bf(acc[ns][cs][2] + bvv);
            h4.w = f2bf(acc[ns][cs][3] + bvv);
            size_t off = (((size_t)b*(KN>>5) + nb*2 + wn)*KC + d)*32 + ns*16 + ty*4;
            *reinterpret_cast<ushort4*>(Vt2 + off) = h4;
        }
    }
}

// ---------------- K3: V-form MFMA flash (branch B), 64-row tiles (round-6 config, unchanged)
__global__ __launch_bounds__(512, 4) void k_flash3(
    const unsigned short* __restrict__ Abf, const unsigned short* __restrict__ Vt2,
    const unsigned short* __restrict__ Fbf, const float* __restrict__ cB,
    float* __restrict__ Vpart, float* __restrict__ lpart,
    int nchunk, int NK, int g_per)
{
    extern __shared__ char smem[];
    unsigned short* a_rm = (unsigned short*)smem;
    unsigned short* p    = (unsigned short*)(smem + 49152);
    float*          redl = (float*)(smem + 58368);

    const int tid = threadIdx.x;
    const int wid = tid >> 6, lane = tid & 63;
    const int tx = lane & 15, ty = lane >> 4;
    const unsigned bid = blockIdx.x;
    const int h = bid / g_per;
    const unsigned g = bid - h*g_per;
    const int b = g / nchunk;
    const int chunk = g - b*nchunk;
    const int n0 = chunk * NK;
    const int wn = wid >> 2, wh = wid & 3;
    const int wph = wid >> 1, wpd = wid & 1;

    bf16x8 ffrag[12];
    {
        const unsigned short* fp = Fbf + ((size_t)(b*KC2 + h*64 + wh*16 + tx))*KC + ty*8;
        #pragma unroll
        for (int kk = 0; kk < 12; ++kk)
            ffrag[kk] = *reinterpret_cast<const bf16x8*>(fp + kk*32);
    }
    const float cbv = cB[(size_t)b*KC2 + h*64 + wh*16 + tx];
    float lacc = 0.f;
    f32x4 Vacc = (f32x4){0.f,0.f,0.f,0.f};

    const unsigned short* atile = Abf + ((size_t)b*KN + n0)*KC;
    #pragma unroll
    for (int i = 0; i < 6; ++i)
        gld_lds16(atile + (size_t)tid*8 + i*4096, a_rm + tid*8 + i*4096);
    __syncthreads();

    const int NT = NK >> 6;
    for (int nt = 0; nt < NT; ++nt) {
        size_t vrow = (size_t)b*(KN >> 5) + ((n0 + nt*64) >> 5);
        bf16x8 vf0 = *reinterpret_cast<const bf16x8*>(
            Vt2 + ((vrow + 0)*KC + h*KD + wpd*16 + tx)*32 + ty*8);
        bf16x8 vf1 = *reinterpret_cast<const bf16x8*>(
            Vt2 + ((vrow + 1)*KC + h*KD + wpd*16 + tx)*32 + ty*8);
        f32x4 tacc[2];
        tacc[0] = (f32x4){0.f,0.f,0.f,0.f};
        tacc[1] = (f32x4){0.f,0.f,0.f,0.f};
        __builtin_amdgcn_s_setprio(1);
        #pragma unroll
        for (int kk = 0; kk < 12; ++kk) {
            #pragma unroll
            for (int ns = 0; ns < 2; ++ns) {
                int n = wn*32 + ns*16 + tx;
                int gs = (kk*4 + ty) ^ (n & 7);
                bf16x8 af = *reinterpret_cast<const bf16x8*>(a_rm + n*384 + gs*8);
                tacc[ns] = MFMA_16x16x32(af, ffrag[kk], tacc[ns], 0, 0, 0);
            }
        }
        __builtin_amdgcn_s_setprio(0);
        #pragma unroll
        for (int ns = 0; ns < 2; ++ns) {
            float e0 = __expf(tacc[ns][0] + cbv);
            float e1 = __expf(tacc[ns][1] + cbv);
            float e2 = __expf(tacc[ns][2] + cbv);
            float e3 = __expf(tacc[ns][3] + cbv);
            lacc += e0 + e1 + e2 + e3;
            int hm = wh*16 + tx;
            int np = wn*32 + ns*16 + ty*4;
            ushort4 h4 = { f2bf(e0), f2bf(e1), f2bf(e2), f2bf(e3) };
            *reinterpret_cast<ushort4*>(p + hm*72 + np) = h4;
        }
        __syncthreads();
        if (nt + 1 < NT) {
            const unsigned short* at = atile + (size_t)(nt+1)*64*KC;
            #pragma unroll
            for (int i = 0; i < 6; ++i)
                gld_lds16(at + (size_t)tid*8 + i*4096, a_rm + tid*8 + i*4096);
        }
        bf16x8 pa0 = *reinterpret_cast<const bf16x8*>(p + (wph*16 + tx)*72 + 0*32 + ty*8);
        bf16x8 pa1 = *reinterpret_cast<const bf16x8*>(p + (wph*16 + tx)*72 + 1*32 + ty*8);
        Vacc = MFMA_16x16x32(pa0, vf0, Vacc, 0, 0, 0);
        Vacc = MFMA_16x16x32(pa1, vf1, Vacc, 0, 0, 0);
        __syncthreads();
    }
    #pragma unroll
    for (int r = 0; r < 4; ++r)
        Vpart[(((size_t)(b*KH + h)*nchunk + chunk)*64 + wph*16 + ty*4 + r)*32 + wpd*16 + tx]
            = Vacc[r];
    lacc += __shfl_xor(lacc, 16);
    lacc += __shfl_xor(lacc, 32);
    if (lane < 16) redl[wn*64 + wh*16 + tx] = lacc;
    __syncthreads();
    if (tid < 64)
        lpart[((size_t)b*KC2 + h*64 + tid)*nchunk + chunk] = redl[tid] + redl[64 + tid];
}

// ---------------- K4: combine3 (fused): x_s = (sum_ch Vpart)/l ; Mt2 = bf16 frag-major(x_s @ Wproj_h)
__global__ __launch_bounds__(384) void k_combine3(
    const float* __restrict__ Vpart, const float* __restrict__ lpart,
    const float* __restrict__ Wproj, unsigned short* __restrict__ Mt2, int nchunk)
{
    __shared__ float xs[64][32];
    __shared__ float invl[64];
    __shared__ float lred[64][4];
    const int h = blockIdx.x, b = blockIdx.y;
    const int tid = threadIdx.x;
    if (tid < 256) {
        int hm = tid >> 2, q = tid & 3;
        float s = 0.f;
        for (int ch = q; ch < nchunk; ch += 4)
            s += lpart[((size_t)b*KC2 + h*64 + hm)*nchunk + ch];
        lred[hm][q] = s;
    }
    __syncthreads();
    if (tid < 64)
        invl[tid] = 1.f / (lred[tid][0] + lred[tid][1] + lred[tid][2] + lred[tid][3]);
    __syncthreads();
    for (int v = tid; v < 2048; v += 384) {
        int hm = v >> 5;
        float u = 0.f;
        const float* vp = Vpart + ((size_t)(b*KH + h)*nchunk)*2048 + v;
        for (int ch = 0; ch < nchunk; ++ch) u += vp[(size_t)ch*2048];
        xs[hm][v & 31] = u * invl[hm];
    }
    __syncthreads();
    const int e = tid;
    float wp[32];
    #pragma unroll
    for (int d = 0; d < 32; ++d) wp[d] = Wproj[(size_t)(h*KD + d)*KC + e];
    #pragma unroll
    for (int half = 0; half < 2; ++half) {
        ushort4 line[8];
        #pragma unroll
        for (int mq = 0; mq < 8; ++mq) {
            float a4[4];
            #pragma unroll
            for (int mr = 0; mr < 4; ++mr) {
                float a = 0.f;
                #pragma unroll
                for (int d = 0; d < 32; ++d)
                    a = fmaf(xs[half*32 + mq*4 + mr][d], wp[d], a);
                a4[mr] = a;
            }
            line[mq] = (ushort4){ f2bf(a4[0]), f2bf(a4[1]), f2bf(a4[2]), f2bf(a4[3]) };
        }
        unsigned short* dst = Mt2 + (((size_t)(b*KH + h)*2 + half)*KC + e)*32;
        #pragma unroll
        for (int q = 0; q < 4; ++q)
            reinterpret_cast<uint4*>(dst)[q] =
                reinterpret_cast<const uint4*>(line)[q];
    }
}

// ---------------- k_qkproj: Q = src @ W + bias -> A-frag-major QAf[b][n>>4][24 w][4 ty][16 row][8 j]
__global__ __launch_bounds__(512, 4) void k_qkproj(
    const float* __restrict__ src, const unsigned short* __restrict__ WT2,
    const float* __restrict__ bias, unsigned short* __restrict__ dstAf)
{
    extern __shared__ char smem[];
    unsigned short* xb = (unsigned short*)smem;   // [64][384] swizzled, 49152B
    const int tid = threadIdx.x;
    const int wid = tid >> 6, lane = tid & 63;
    const int tx = lane & 15, ty = lane >> 4;
    const int nb = blockIdx.x, b = blockIdx.y, z = blockIdx.z;

    {   // stage xb (swizzled bf16 from f32 src)
        const float4* s4 = reinterpret_cast<const float4*>(src + ((size_t)(b*KN + nb*64))*KC);
        #pragma unroll
        for (int i = 0; i < 12; ++i) {
            int f = tid + i*512;
            int n = f / 96, c4 = f % 96;
            float4 v = s4[f];
            ushort4 h4 = { f2bf(v.x), f2bf(v.y), f2bf(v.z), f2bf(v.w) };
            int g = c4 >> 1, half = c4 & 1;
            int gs = g ^ (n & 7);
            *reinterpret_cast<ushort4*>(xb + n*384 + gs*8 + half*4) = h4;
        }
    }
    f32x4 acc[4][3];
    #pragma unroll
    for (int i = 0; i < 4; ++i)
        #pragma unroll
        for (int j = 0; j < 3; ++j) acc[i][j] = (f32x4){0.f,0.f,0.f,0.f};
    __syncthreads();

    #pragma unroll
    for (int kk = 0; kk < 12; ++kk) {
        bf16x8 af[4];
        #pragma unroll
        for (int ng = 0; ng < 4; ++ng) {
            int n = ng*16 + tx;
            int gs = (kk*4 + ty) ^ (n & 7);
            af[ng] = *reinterpret_cast<const bf16x8*>(xb + n*384 + gs*8);
        }
        #pragma unroll
        for (int cs = 0; cs < 3; ++cs) {
            int col = z*KC + wid*48 + cs*16 + tx;
            bf16x8 bf = *reinterpret_cast<const bf16x8*>(WT2 + ((size_t)kk*KC2 + col)*32 + ty*8);
            #pragma unroll
            for (int ng = 0; ng < 4; ++ng)
                acc[ng][cs] = MFMA_16x16x32(af[ng], bf, acc[ng][cs], 0, 0, 0);
        }
    }
    // epilogue: +bias, scatter to A-frag-major layout
    #pragma unroll
    for (int cs = 0; cs < 3; ++cs) {
        int col = z*KC + wid*48 + cs*16 + tx;
        float bv = bias[col];
        int w = col >> 5, tyq = (col >> 3) & 3, j = col & 7;
        #pragma unroll
        for (int ng = 0; ng < 4; ++ng) {
            int nt = nb*4 + ng;
            size_t base = ((((size_t)(b*256 + nt)*24 + w)*4 + tyq)*16)*8 + j;
            #pragma unroll
            for (int r = 0; r < 4; ++r) {
                int row = ty*4 + r;
                dstAf[base + (size_t)row*8] = f2bf(acc[ng][cs][r] + bv);
            }
        }
    }
}

// ---------------- K5: k_out4 (branch A, Q-factored): QK^T = q·k (K=32, 2 branches)
// LDS: p [64][140] bf16 @0 (17920); red [2][64][4] f32 @17920 (2048); total 19968
__global__ __launch_bounds__(512, 4) void k_out4(
    const unsigned short* __restrict__ QAf, const unsigned short* __restrict__ KA,
    const float* __restrict__ ba, const unsigned short* __restrict__ Mt2,
    const float* __restrict__ bproj, float* __restrict__ out)
{
    extern __shared__ char smem[];
    unsigned short* p = (unsigned short*)smem;          // pitch 140
    float* red = (float*)(smem + 17920);                // [2][64][4]

    const int tid = threadIdx.x;
    const int wid = tid >> 6, lane = tid & 63;
    const int tx = lane & 15, ty = lane >> 4;
    const int nb = blockIdx.x, b = blockIdx.y;
    const int hq2 = wid >> 2, wm = wid & 3;   // QK^T: head-of-pair, m-slice
    const int es = wid * 48;                  // PV: e-slice
    const float ba0 = ba[0];

    f32x4 oacc[4][3];
    #pragma unroll
    for (int i = 0; i < 4; ++i)
        #pragma unroll
        for (int j = 0; j < 3; ++j) oacc[i][j] = (f32x4){0.f,0.f,0.f,0.f};

    for (int it = 0; it < 6; ++it) {
        const int hq = it*2 + hq2;
        // B-frags (tiny, L2-hot): branch 0 w=hq, branch 1 w=12+hq
        bf16x8 kb0 = *reinterpret_cast<const bf16x8*>(
            KA + ((size_t)(b*24 + hq)*64 + wm*16 + tx)*32 + ty*8);
        bf16x8 kb1 = *reinterpret_cast<const bf16x8*>(
            KA + ((size_t)(b*24 + 12 + hq)*64 + wm*16 + tx)*32 + ty*8);
        // ---- QK^T: wave computes [64 n][16 m]; A-frags stream coalesced from QAf
        f32x4 tacc[4];
        #pragma unroll
        for (int ng = 0; ng < 4; ++ng) tacc[ng] = (f32x4){0.f,0.f,0.f,0.f};
        __builtin_amdgcn_s_setprio(1);
        #pragma unroll
        for (int ng = 0; ng < 4; ++ng) {
            const unsigned short* ap = QAf +
                (((size_t)(b*256 + nb*4 + ng)*24 + hq)*64 + lane)*8;
            bf16x8 a0 = *reinterpret_cast<const bf16x8*>(ap);
            bf16x8 a1 = *reinterpret_cast<const bf16x8*>(ap + 12*512);
            tacc[ng] = MFMA_16x16x32(a0, kb0, tacc[ng], 0, 0, 0);
            tacc[ng] = MFMA_16x16x32(a1, kb1, tacc[ng], 0, 0, 0);
        }
        __builtin_amdgcn_s_setprio(0);
        // ---- exp + partial row-sum over this wave's 16 m
        float s[4][4];
        #pragma unroll
        for (int ng = 0; ng < 4; ++ng)
            #pragma unroll
            for (int r = 0; r < 4; ++r) {
                tacc[ng][r] = __expf(tacc[ng][r] + ba0);
                s[ng][r] = tacc[ng][r];
            }
        #pragma unroll
        for (int mask = 1; mask < 16; mask <<= 1)
            #pragma unroll
            for (int ng = 0; ng < 4; ++ng)
                #pragma unroll
                for (int r = 0; r < 4; ++r)
                    s[ng][r] += __shfl_xor(s[ng][r], mask);
        if (tx == 0) {
            #pragma unroll
            for (int ng = 0; ng < 4; ++ng)
                #pragma unroll
                for (int r = 0; r < 4; ++r)
                    red[(hq2*64 + ng*16 + ty*4 + r)*4 + wm] = s[ng][r];
        }
        __syncthreads();   // red visible; prev PV p-reads done
        // ---- normalize + write P bf16 into p[n][hq2*64 + wm*16 + tx]
        #pragma unroll
        for (int ng = 0; ng < 4; ++ng)
            #pragma unroll
            for (int r = 0; r < 4; ++r) {
                int n = ng*16 + ty*4 + r;
                float4 rv = *reinterpret_cast<const float4*>(red + (hq2*64 + n)*4);
                float inv = 1.f / (rv.x + rv.y + rv.z + rv.w);
                p[n*140 + hq2*64 + wm*16 + tx] = f2bf(tacc[ng][r] * inv);
            }
        __syncthreads();   // p visible
        // ---- PV: oacc += P[64 n][128 k] @ M2[128 k][48 e-slice]
        __builtin_amdgcn_s_setprio(1);
        #pragma unroll
        for (int ks = 0; ks < 4; ++ks) {
            const int hM = it*2 + (ks >> 1);
            const int inner = ks & 1;
            bf16x8 pa[4];
            #pragma unroll
            for (int ng = 0; ng < 4; ++ng)
                pa[ng] = *reinterpret_cast<const bf16x8*>(
                    p + (ng*16 + tx)*140 + ks*32 + ty*8);
            #pragma unroll
            for (int j = 0; j < 3; ++j) {
                bf16x8 mf = *reinterpret_cast<const bf16x8*>(
                    Mt2 + (((size_t)(b*KH + hM)*2 + inner)*KC + es + j*16 + tx)*32 + ty*8);
                #pragma unroll
                for (int ng = 0; ng < 4; ++ng)
                    oacc[ng][j] = MFMA_16x16x32(pa[ng], mf, oacc[ng][j], 0, 0, 0);
            }
        }
        __builtin_amdgcn_s_setprio(0);
    }
    // epilogue
    float bp[3];
    #pragma unroll
    for (int j = 0; j < 3; ++j) bp[j] = bproj[es + j*16 + tx];
    #pragma unroll
    for (int ng = 0; ng < 4; ++ng)
        #pragma unroll
        for (int r = 0; r < 4; ++r) {
            size_t base = (size_t)(b*KN + nb*64 + ng*16 + ty*4 + r)*KC;
            #pragma unroll
            for (int j = 0; j < 3; ++j)
                out[base + es + j*16 + tx] = oacc[ng][j][r] + bp[j];
        }
}

extern "C" void kernel_launch(void* const* d_in, const int* in_sizes, int n_in,
                              void* d_out, int out_size, void* d_ws, size_t ws_size,
                              hipStream_t stream) {
    const float* x     = (const float*)d_in[0];
    const float* attn  = (const float*)d_in[1];
    const float* agent = (const float*)d_in[2];
    const float* Wq_lf = (const float*)d_in[3];
    const float* bq_lf = (const float*)d_in[4];
    const float* Wk_ag = (const float*)d_in[5];
    const float* bk_ag = (const float*)d_in[6];
    const float* wa    = (const float*)d_in[7];
    const float* ba    = (const float*)d_in[8];
    const float* Wq_ag = (const float*)d_in[9];
    const float* bq_ag = (const float*)d_in[10];
    const float* Wk_hf = (const float*)d_in[11];
    const float* bk_hf = (const float*)d_in[12];
    const float* Wv_hf = (const float*)d_in[13];
    const float* bv_hf = (const float*)d_in[14];
    const float* wb    = (const float*)d_in[15];
    const float* bb    = (const float*)d_in[16];
    const float* Wproj = (const float*)d_in[17];
    const float* bproj = (const float*)d_in[18];
    float* out = (float*)d_out;
    float* ws  = (float*)d_ws;

    // workspace layout (f32 units) — total 19759104 f32 = 79.04 MB (ws >= 81.9 MB proven)
    const size_t o_Kag  = 0;          // 393216
    const size_t o_Qa   = 393216;     // 393216
    const size_t o_cA   = 786432;     // 6144 (unused output of build_c)
    const size_t o_cB   = 792576;     // 6144
    const size_t o_Fbf  = 798720;     // 1179648
    const size_t o_WkT  = 1978368;    // 294912
    const size_t o_WvT2 = 2273280;    // 36864
    const size_t o_WqT2 = 2310144;    // 147456
    const size_t o_KA   = 2457600;    // 196608
    const size_t o_Mt2  = 2654208;    // 1179648
    const size_t o_Abf  = 3833856;    // 3145728 (dead after flash3)
    const size_t o_Vt2  = 6979584;    // 6291456 (dead after flash3)
    const size_t o_lp   = 13271040;   // 196608 (nchunk=32; dead after combine3)
    const size_t o_Vp   = 13467648;   // 6291456 (dead after combine3)
    // QAf (12582912) overlays [o_Abf .. end) after flash3+combine3 complete
    const size_t o_QAf  = 3833856;
    const int nchunk = 32;
    (void)ws_size; (void)in_sizes; (void)n_in; (void)out_size;

    unsigned short* Fbf  = (unsigned short*)(ws + o_Fbf);
    unsigned short* WvT2 = (unsigned short*)(ws + o_WvT2);
    unsigned short* WqT2 = (unsigned short*)(ws + o_WqT2);
    unsigned short* KA   = (unsigned short*)(ws + o_KA);
    unsigned short* Mt2  = (unsigned short*)(ws + o_Mt2);
    unsigned short* Abf  = (unsigned short*)(ws + o_Abf);
    unsigned short* Vt2  = (unsigned short*)(ws + o_Vt2);
    unsigned short* QAf  = (unsigned short*)(ws + o_QAf);

    k_agent_proj<<<dim3(64, 2), 256, 0, stream>>>(agent, Wk_ag, bk_ag, Wq_ag, bq_ag,
                                                  ws + o_Kag, ws + o_Qa);
    k_transpose<<<dim3(24, 12), dim3(32, 8), 0, stream>>>(Wk_hf, ws + o_WkT);
    // Wq_lf [384][768] -> WqT2 frag-major [12][768][32]
    k_tcastT<<<dim3(6, 12, 1), 256, 0, stream>>>(Wq_lf, WqT2, nullptr,
                                                 KC, KC2, 0, 0, 0);
    k_kabuild<<<dim3(KB), 256, 0, stream>>>(ws + o_Kag, wa, KA);
    k_build_F<<<dim3(96, 8), 128, 0, stream>>>(ws + o_WkT, ws + o_Qa, wb, Fbf);
    k_build_c<<<8, 256, 0, stream>>>(bq_lf, ws + o_Kag, wa, ba, bk_hf, ws + o_Qa,
                                     wb, bb, ws + o_cA, ws + o_cB);
    // attn -> Abf (swizzled row-major bf16)
    k_tcastT<<<dim3(64, 6, 8), 256, 0, stream>>>(attn, nullptr, Abf,
                                                 KN, KC, (long)KN*KC, 0, (long)KN*KC);
    // Wv [384][384] -> WvT2 frag-major
    k_tcastT<<<dim3(6, 6, 1), 256, 0, stream>>>(Wv_hf, WvT2, nullptr,
                                                 KC, KC, 0, 0, 0);

    const int vp_lds = 49152;
    const int fl_lds = 58880;
    const int qp_lds = 49152;
    const int ko_lds = 19968;
    (void)hipFuncSetAttribute(reinterpret_cast<const void*>(k_vproj),
                              hipFuncAttributeMaxDynamicSharedMemorySize, vp_lds);
    (void)hipFuncSetAttribute(reinterpret_cast<const void*>(k_flash3),
                              hipFuncAttributeMaxDynamicSharedMemorySize, fl_lds);
    (void)hipFuncSetAttribute(reinterpret_cast<const void*>(k_qkproj),
                              hipFuncAttributeMaxDynamicSharedMemorySize, qp_lds);
    (void)hipFuncSetAttribute(reinterpret_cast<const void*>(k_out4),
                              hipFuncAttributeMaxDynamicSharedMemorySize, ko_lds);

    k_vproj<<<dim3(KN/64, KB), 512, vp_lds, stream>>>(Abf, WvT2, bv_hf, Vt2);

    const int g_per = KB * nchunk;   // 256
    k_flash3<<<dim3(KH * g_per), 512, fl_lds, stream>>>(
        Abf, Vt2, Fbf, ws + o_cB, ws + o_Vp, ws + o_lp, nchunk, KN / nchunk, g_per);
    k_combine3<<<dim3(KH, KB), 384, 0, stream>>>(
        ws + o_Vp, ws + o_lp, Wproj, Mt2, nchunk);
    // Q = x @ Wq_lf + bq -> QAf (overlays dead flash-region)
    k_qkproj<<<dim3(KN/64, KB, 2), 512, qp_lds, stream>>>(x, WqT2, bq_lf, QAf);
    k_out4<<<dim3(KN/64, KB), 512, ko_lds, stream>>>(
        QAf, KA, ba, Mt2, bproj, out);
}

// Round 10
// 352.687 us; speedup vs baseline: 1.2714x; 1.1115x over previous
//
#include <hip/hip_runtime.h>

#define KB 8
#define KN 4096
#define KNA 64
#define KH 12
#define KD 32
#define KC 384
#define KC2 768
#define KSCALE 0.17677669529663688f

typedef __bf16 bf16x8 __attribute__((ext_vector_type(8)));
typedef float  f32x4  __attribute__((ext_vector_type(4)));

static __device__ __forceinline__ unsigned short f2bf(float f) {
    unsigned int u = __builtin_bit_cast(unsigned int, f);
    u += 0x7FFFu + ((u >> 16) & 1u);
    return (unsigned short)(u >> 16);
}

static __device__ __forceinline__ void gld_lds16(const unsigned short* g, unsigned short* l) {
    __builtin_amdgcn_global_load_lds(
        (const __attribute__((address_space(1))) unsigned int*)g,
        (__attribute__((address_space(3))) unsigned int*)l, 16, 0, 0);
}

#define MFMA_16x16x32 __builtin_amdgcn_mfma_f32_16x16x32_bf16

// ---------------- K0: Kag = agent@Wk_ag + bk ; Qa = agent@Wq_ag + bq
__global__ __launch_bounds__(256) void k_agent_proj(
    const float* __restrict__ agent,
    const float* __restrict__ Wk_ag, const float* __restrict__ bk_ag,
    const float* __restrict__ Wq_ag, const float* __restrict__ bq_ag,
    float* __restrict__ Kag, float* __restrict__ Qa)
{
    __shared__ float a_lds[8][KC];
    const int tid = threadIdx.x;
    const int rg  = blockIdx.x;
    const float* W    = blockIdx.y ? Wq_ag : Wk_ag;
    const float* bias = blockIdx.y ? bq_ag : bk_ag;
    float* dst        = blockIdx.y ? Qa    : Kag;

    const float4* src4 = reinterpret_cast<const float4*>(agent) + (size_t)rg * 768;
    float4* al4 = reinterpret_cast<float4*>(&a_lds[0][0]);
    #pragma unroll
    for (int l = 0; l < 3; ++l) al4[tid + l*256] = src4[tid + l*256];
    __syncthreads();

    float acc[8][3] = {};
    for (int c = 0; c < KC; ++c) {
        float w0 = W[(size_t)c*KC2 + tid];
        float w1 = W[(size_t)c*KC2 + tid + 256];
        float w2 = W[(size_t)c*KC2 + tid + 512];
        #pragma unroll
        for (int r = 0; r < 8; ++r) {
            float a = a_lds[r][c];
            acc[r][0] = fmaf(a, w0, acc[r][0]);
            acc[r][1] = fmaf(a, w1, acc[r][1]);
            acc[r][2] = fmaf(a, w2, acc[r][2]);
        }
    }
    float b0 = bias[tid], b1 = bias[tid+256], b2 = bias[tid+512];
    #pragma unroll
    for (int r = 0; r < 8; ++r) {
        size_t base = (size_t)(rg*8 + r) * KC2;
        dst[base + tid      ] = acc[r][0] + b0;
        dst[base + tid + 256] = acc[r][1] + b1;
        dst[base + tid + 512] = acc[r][2] + b2;
    }
}

// ---------------- transpose Wk_hf [384,768] -> WkT [768,384] (f32)
__global__ __launch_bounds__(256) void k_transpose(
    const float* __restrict__ Win, float* __restrict__ Wout)
{
    __shared__ float tile[32][33];
    const int tx = threadIdx.x, ty = threadIdx.y;
    const int j0 = blockIdx.x * 32, c0 = blockIdx.y * 32;
    #pragma unroll
    for (int yy = 0; yy < 4; ++yy)
        tile[ty + yy*8][tx] = Win[(size_t)(c0 + ty + yy*8)*KC2 + j0 + tx];
    __syncthreads();
    #pragma unroll
    for (int yy = 0; yy < 4; ++yy)
        Wout[(size_t)(j0 + ty + yy*8)*KC + c0 + tx] = tile[tx][ty + yy*8];
}

// ---------------- tcastT: src f32 [R][C] -> dstT bf16 frag-major [(r>>5)][C][32]
__global__ __launch_bounds__(256) void k_tcastT(
    const float* __restrict__ src, unsigned short* __restrict__ dstT,
    unsigned short* __restrict__ dstRM,
    int R, int C, long sstride, long dTstride, long dRMstride)
{
    __shared__ unsigned short lds[64][80];
    const int t = threadIdx.x;
    const int r0 = blockIdx.x * 64, c0 = blockIdx.y * 64;
    const float* s = src + (size_t)blockIdx.z * sstride;
    #pragma unroll
    for (int i = 0; i < 16; ++i) {
        int f = t + i*256; int rr = f >> 6, cc = f & 63;
        lds[rr][cc] = f2bf(s[(size_t)(r0+rr)*C + c0 + cc]);
    }
    __syncthreads();
    if (dstT) {
        unsigned short* dT = dstT + (size_t)blockIdx.z * dTstride;
        #pragma unroll
        for (int i = 0; i < 8; ++i) {
            int o = t + i*256;
            int chunk = o >> 10, c = (o >> 4) & 63, pair = o & 15;
            int r = chunk*32 + pair*2;
            unsigned int v = (unsigned int)lds[r][c] | ((unsigned int)lds[r+1][c] << 16);
            size_t off = ((size_t)((r0>>5) + chunk)*C + c0 + c)*32 + pair*2;
            *reinterpret_cast<unsigned int*>(dT + off) = v;
        }
    }
    if (dstRM) {
        unsigned short* dR = dstRM + (size_t)blockIdx.z * dRMstride;
        #pragma unroll
        for (int i = 0; i < 2; ++i) {
            int idx = t*2 + i;
            int n = idx >> 3, gt = idx & 7;
            int g = (c0 >> 3) + gt;
            int slot = g ^ ((r0 + n) & 7);
            *reinterpret_cast<bf16x8*>(dR + (size_t)(r0+n)*C + slot*8) =
                *reinterpret_cast<const bf16x8*>(&lds[n][gt*8]);
        }
    }
}

// ---------------- K2b: F_bf[b][hm][c] bf16 row-major (branch-B scores)
__global__ __launch_bounds__(128) void k_build_F(
    const float* __restrict__ WkT, const float* __restrict__ Qa,
    const float* __restrict__ wb, unsigned short* __restrict__ Fbf)
{
    __shared__ float q_lds[8][64];
    const int tid = threadIdx.x;
    const int g = blockIdx.x;
    const int b = blockIdx.y;
    const int h = (g*8) >> 6;
    const float t0 = KSCALE*wb[0], t1 = KSCALE*wb[1];
    #pragma unroll
    for (int l = 0; l < 4; ++l) {
        int v = tid + l*128;
        int i = v >> 6, d = v & 63;
        int m = (g*8 + i) & 63;
        int jj   = (d < KD) ? (h*KD + d) : (KC + h*KD + d - KD);
        float cf = (d < KD) ? t0 : t1;
        q_lds[i][d] = cf * Qa[(size_t)(b*KNA + m)*KC2 + jj];
    }
    __syncthreads();
    float acc[8][3] = {};
    for (int d = 0; d < 64; ++d) {
        int row = (d < KD) ? (h*KD + d) : (KC + h*KD + d - KD);
        const float* wr = WkT + (size_t)row*KC;
        float w0 = wr[tid], w1 = wr[tid+128], w2 = wr[tid+256];
        #pragma unroll
        for (int i = 0; i < 8; ++i) {
            float q = q_lds[i][d];
            acc[i][0] = fmaf(q, w0, acc[i][0]);
            acc[i][1] = fmaf(q, w1, acc[i][1]);
            acc[i][2] = fmaf(q, w2, acc[i][2]);
        }
    }
    #pragma unroll
    for (int i = 0; i < 8; ++i)
        #pragma unroll
        for (int l = 0; l < 3; ++l)
            Fbf[((size_t)b*KC2 + g*8 + i)*KC + tid + l*128] = f2bf(acc[i][l]);
}

// ---------------- k_kabc: KA (scaled K bf16 frag-major) + cB bias constants
__global__ __launch_bounds__(256) void k_kabc(
    const float* __restrict__ Kag, const float* __restrict__ Qa,
    const float* __restrict__ wa, const float* __restrict__ bk_hf,
    const float* __restrict__ wb, const float* __restrict__ bbv,
    unsigned short* __restrict__ KA, float* __restrict__ cB)
{
    const int b = blockIdx.x, tid = threadIdx.x;
    const float s0 = KSCALE * wa[0], s1 = KSCALE * wa[1];
    #pragma unroll
    for (int i = 0; i < 24; ++i) {
        int v = tid + i*256;
        int w = v >> 8, m = (v >> 2) & 63, k8 = v & 3;
        float sc = (w >= 12) ? s1 : s0;
        const float* sp = Kag + ((size_t)(b*KNA + m))*KC2 + w*32 + k8*8;
        float4 f0 = *reinterpret_cast<const float4*>(sp);
        float4 f1 = *reinterpret_cast<const float4*>(sp + 4);
        ushort4 h0 = { f2bf(f0.x*sc), f2bf(f0.y*sc), f2bf(f0.z*sc), f2bf(f0.w*sc) };
        ushort4 h1 = { f2bf(f1.x*sc), f2bf(f1.y*sc), f2bf(f1.z*sc), f2bf(f1.w*sc) };
        unsigned short* dp = KA + ((size_t)(b*24 + w)*64 + m)*32 + k8*8;
        *reinterpret_cast<ushort4*>(dp)     = h0;
        *reinterpret_cast<ushort4*>(dp + 4) = h1;
    }
    const float t0 = KSCALE*wb[0], t1 = KSCALE*wb[1];
    for (int hm = tid; hm < KC2; hm += 256) {
        int h = hm >> 6, m = hm & 63;
        const float* qp = Qa + (size_t)(b*KNA + m)*KC2;
        float bb2 = 0.f;
        for (int d = 0; d < KD; ++d)
            bb2 += t0*bk_hf[h*KD+d]*qp[h*KD+d] + t1*bk_hf[KC+h*KD+d]*qp[KC+h*KD+d];
        cB[(size_t)b*KC2 + hm] = bb2 + bbv[0];
    }
}

// ---------------- k_vproj2: reads attn f32; writes Abf (swizzled bf16) + Vt2 (frag-major)
__global__ __launch_bounds__(512, 4) void k_vproj2(
    const float* __restrict__ attn, const unsigned short* __restrict__ WvT2,
    const float* __restrict__ bv, unsigned short* __restrict__ Abf,
    unsigned short* __restrict__ Vt2)
{
    extern __shared__ char smem[];
    unsigned short* a_rm = (unsigned short*)smem;   // 49152B
    const int tid = threadIdx.x;
    const int wid = tid >> 6, lane = tid & 63;
    const int tx = lane & 15, ty = lane >> 4;
    const int nb = blockIdx.x, b = blockIdx.y;
    const int wn = wid >> 2, wd = wid & 3;

    {   // stage from f32 + write Abf side-product
        const float4* src = reinterpret_cast<const float4*>(attn + ((size_t)(b*KN + nb*64))*KC);
        unsigned short* ab = Abf + ((size_t)(b*KN + nb*64))*KC;
        #pragma unroll
        for (int i = 0; i < 12; ++i) {
            int f = tid + i*512;
            int n = f / 96, c4 = f % 96;
            float4 v = src[f];
            ushort4 h4 = { f2bf(v.x), f2bf(v.y), f2bf(v.z), f2bf(v.w) };
            int g = c4 >> 1, half = c4 & 1;
            int gs = g ^ (n & 7);
            *reinterpret_cast<ushort4*>(a_rm + n*384 + gs*8 + half*4) = h4;
            *reinterpret_cast<ushort4*>(ab + (size_t)n*384 + gs*8 + half*4) = h4;
        }
    }
    f32x4 acc[2][6];
    #pragma unroll
    for (int i = 0; i < 2; ++i)
        #pragma unroll
        for (int j = 0; j < 6; ++j) acc[i][j] = (f32x4){0.f,0.f,0.f,0.f};
    __syncthreads();

    #pragma unroll
    for (int kk = 0; kk < 12; ++kk) {
        bf16x8 af[2];
        #pragma unroll
        for (int ns = 0; ns < 2; ++ns) {
            int n = wn*32 + ns*16 + tx;
            int gs = (kk*4 + ty) ^ (n & 7);
            af[ns] = *reinterpret_cast<const bf16x8*>(a_rm + n*384 + gs*8);
        }
        #pragma unroll
        for (int cs = 0; cs < 6; ++cs) {
            int d = wd*96 + cs*16 + tx;
            bf16x8 bf = *reinterpret_cast<const bf16x8*>(WvT2 + ((size_t)kk*KC + d)*32 + ty*8);
            #pragma unroll
            for (int ns = 0; ns < 2; ++ns)
                acc[ns][cs] = MFMA_16x16x32(af[ns], bf, acc[ns][cs], 0, 0, 0);
        }
    }
    #pragma unroll
    for (int cs = 0; cs < 6; ++cs) {
        int d = wd*96 + cs*16 + tx;
        float bvv = bv[d];
        #pragma unroll
        for (int ns = 0; ns < 2; ++ns) {
            ushort4 h4;
            h4.x = f2bf(acc[ns][cs][0] + bvv);
            h4.y = f2bf(acc[ns][cs][1] + bvv);
            h4.z = f2bf(acc[ns][cs][2] + bvv);
            h4.w = f2bf(acc[ns][cs][3] + bvv);
            size_t off = (((size_t)b*(KN>>5) + nb*2 + wn)*KC + d)*32 + ns*16 + ty*4;
            *reinterpret_cast<ushort4*>(Vt2 + off) = h4;
        }
    }
}

// ---------------- K3: V-form MFMA flash (branch B), 64-row tiles (round-6 config)
__global__ __launch_bounds__(512, 4) void k_flash3(
    const unsigned short* __restrict__ Abf, const unsigned short* __restrict__ Vt2,
    const unsigned short* __restrict__ Fbf, const float* __restrict__ cB,
    float* __restrict__ Vpart, float* __restrict__ lpart,
    int nchunk, int NK, int g_per)
{
    extern __shared__ char smem[];
    unsigned short* a_rm = (unsigned short*)smem;
    unsigned short* p    = (unsigned short*)(smem + 49152);
    float*          redl = (float*)(smem + 58368);

    const int tid = threadIdx.x;
    const int wid = tid >> 6, lane = tid & 63;
    const int tx = lane & 15, ty = lane >> 4;
    const unsigned bid = blockIdx.x;
    const int h = bid / g_per;
    const unsigned g = bid - h*g_per;
    const int b = g / nchunk;
    const int chunk = g - b*nchunk;
    const int n0 = chunk * NK;
    const int wn = wid >> 2, wh = wid & 3;
    const int wph = wid >> 1, wpd = wid & 1;

    bf16x8 ffrag[12];
    {
        const unsigned short* fp = Fbf + ((size_t)(b*KC2 + h*64 + wh*16 + tx))*KC + ty*8;
        #pragma unroll
        for (int kk = 0; kk < 12; ++kk)
            ffrag[kk] = *reinterpret_cast<const bf16x8*>(fp + kk*32);
    }
    const float cbv = cB[(size_t)b*KC2 + h*64 + wh*16 + tx];
    float lacc = 0.f;
    f32x4 Vacc = (f32x4){0.f,0.f,0.f,0.f};

    const unsigned short* atile = Abf + ((size_t)b*KN + n0)*KC;
    #pragma unroll
    for (int i = 0; i < 6; ++i)
        gld_lds16(atile + (size_t)tid*8 + i*4096, a_rm + tid*8 + i*4096);
    __syncthreads();

    const int NT = NK >> 6;
    for (int nt = 0; nt < NT; ++nt) {
        size_t vrow = (size_t)b*(KN >> 5) + ((n0 + nt*64) >> 5);
        bf16x8 vf0 = *reinterpret_cast<const bf16x8*>(
            Vt2 + ((vrow + 0)*KC + h*KD + wpd*16 + tx)*32 + ty*8);
        bf16x8 vf1 = *reinterpret_cast<const bf16x8*>(
            Vt2 + ((vrow + 1)*KC + h*KD + wpd*16 + tx)*32 + ty*8);
        f32x4 tacc[2];
        tacc[0] = (f32x4){0.f,0.f,0.f,0.f};
        tacc[1] = (f32x4){0.f,0.f,0.f,0.f};
        __builtin_amdgcn_s_setprio(1);
        #pragma unroll
        for (int kk = 0; kk < 12; ++kk) {
            #pragma unroll
            for (int ns = 0; ns < 2; ++ns) {
                int n = wn*32 + ns*16 + tx;
                int gs = (kk*4 + ty) ^ (n & 7);
                bf16x8 af = *reinterpret_cast<const bf16x8*>(a_rm + n*384 + gs*8);
                tacc[ns] = MFMA_16x16x32(af, ffrag[kk], tacc[ns], 0, 0, 0);
            }
        }
        __builtin_amdgcn_s_setprio(0);
        #pragma unroll
        for (int ns = 0; ns < 2; ++ns) {
            float e0 = __expf(tacc[ns][0] + cbv);
            float e1 = __expf(tacc[ns][1] + cbv);
            float e2 = __expf(tacc[ns][2] + cbv);
            float e3 = __expf(tacc[ns][3] + cbv);
            lacc += e0 + e1 + e2 + e3;
            int hm = wh*16 + tx;
            int np = wn*32 + ns*16 + ty*4;
            ushort4 h4 = { f2bf(e0), f2bf(e1), f2bf(e2), f2bf(e3) };
            *reinterpret_cast<ushort4*>(p + hm*72 + np) = h4;
        }
        __syncthreads();
        if (nt + 1 < NT) {
            const unsigned short* at = atile + (size_t)(nt+1)*64*KC;
            #pragma unroll
            for (int i = 0; i < 6; ++i)
                gld_lds16(at + (size_t)tid*8 + i*4096, a_rm + tid*8 + i*4096);
        }
        bf16x8 pa0 = *reinterpret_cast<const bf16x8*>(p + (wph*16 + tx)*72 + 0*32 + ty*8);
        bf16x8 pa1 = *reinterpret_cast<const bf16x8*>(p + (wph*16 + tx)*72 + 1*32 + ty*8);
        Vacc = MFMA_16x16x32(pa0, vf0, Vacc, 0, 0, 0);
        Vacc = MFMA_16x16x32(pa1, vf1, Vacc, 0, 0, 0);
        __syncthreads();
    }
    #pragma unroll
    for (int r = 0; r < 4; ++r)
        Vpart[(((size_t)(b*KH + h)*nchunk + chunk)*64 + wph*16 + ty*4 + r)*32 + wpd*16 + tx]
            = Vacc[r];
    lacc += __shfl_xor(lacc, 16);
    lacc += __shfl_xor(lacc, 32);
    if (lane < 16) redl[wn*64 + wh*16 + tx] = lacc;
    __syncthreads();
    if (tid < 64)
        lpart[((size_t)b*KC2 + h*64 + tid)*nchunk + chunk] = redl[tid] + redl[64 + tid];
}

// ---------------- K4: combine3 (fused): x_s = (sum_ch Vpart)/l ; Mt2 = bf16 frag-major
__global__ __launch_bounds__(384) void k_combine3(
    const float* __restrict__ Vpart, const float* __restrict__ lpart,
    const float* __restrict__ Wproj, unsigned short* __restrict__ Mt2, int nchunk)
{
    __shared__ float xs[64][32];
    __shared__ float invl[64];
    __shared__ float lred[64][4];
    const int h = blockIdx.x, b = blockIdx.y;
    const int tid = threadIdx.x;
    if (tid < 256) {
        int hm = tid >> 2, q = tid & 3;
        float s = 0.f;
        for (int ch = q; ch < nchunk; ch += 4)
            s += lpart[((size_t)b*KC2 + h*64 + hm)*nchunk + ch];
        lred[hm][q] = s;
    }
    __syncthreads();
    if (tid < 64)
        invl[tid] = 1.f / (lred[tid][0] + lred[tid][1] + lred[tid][2] + lred[tid][3]);
    __syncthreads();
    for (int v = tid; v < 2048; v += 384) {
        int hm = v >> 5;
        float u = 0.f;
        const float* vp = Vpart + ((size_t)(b*KH + h)*nchunk)*2048 + v;
        for (int ch = 0; ch < nchunk; ++ch) u += vp[(size_t)ch*2048];
        xs[hm][v & 31] = u * invl[hm];
    }
    __syncthreads();
    const int e = tid;
    float wp[32];
    #pragma unroll
    for (int d = 0; d < 32; ++d) wp[d] = Wproj[(size_t)(h*KD + d)*KC + e];
    #pragma unroll
    for (int half = 0; half < 2; ++half) {
        ushort4 line[8];
        #pragma unroll
        for (int mq = 0; mq < 8; ++mq) {
            float a4[4];
            #pragma unroll
            for (int mr = 0; mr < 4; ++mr) {
                float a = 0.f;
                #pragma unroll
                for (int d = 0; d < 32; ++d)
                    a = fmaf(xs[half*32 + mq*4 + mr][d], wp[d], a);
                a4[mr] = a;
            }
            line[mq] = (ushort4){ f2bf(a4[0]), f2bf(a4[1]), f2bf(a4[2]), f2bf(a4[3]) };
        }
        unsigned short* dst = Mt2 + (((size_t)(b*KH + h)*2 + half)*KC + e)*32;
        #pragma unroll
        for (int q = 0; q < 4; ++q)
            reinterpret_cast<uint4*>(dst)[q] =
                reinterpret_cast<const uint4*>(line)[q];
    }
}

// ---------------- k_qkproj: Q = src @ W + bias -> A-frag-major QAf
__global__ __launch_bounds__(512, 4) void k_qkproj(
    const float* __restrict__ src, const unsigned short* __restrict__ WT2,
    const float* __restrict__ bias, unsigned short* __restrict__ dstAf)
{
    extern __shared__ char smem[];
    unsigned short* xb = (unsigned short*)smem;
    const int tid = threadIdx.x;
    const int wid = tid >> 6, lane = tid & 63;
    const int tx = lane & 15, ty = lane >> 4;
    const int nb = blockIdx.x, b = blockIdx.y, z = blockIdx.z;

    {
        const float4* s4 = reinterpret_cast<const float4*>(src + ((size_t)(b*KN + nb*64))*KC);
        #pragma unroll
        for (int i = 0; i < 12; ++i) {
            int f = tid + i*512;
            int n = f / 96, c4 = f % 96;
            float4 v = s4[f];
            ushort4 h4 = { f2bf(v.x), f2bf(v.y), f2bf(v.z), f2bf(v.w) };
            int g = c4 >> 1, half = c4 & 1;
            int gs = g ^ (n & 7);
            *reinterpret_cast<ushort4*>(xb + n*384 + gs*8 + half*4) = h4;
        }
    }
    f32x4 acc[4][3];
    #pragma unroll
    for (int i = 0; i < 4; ++i)
        #pragma unroll
        for (int j = 0; j < 3; ++j) acc[i][j] = (f32x4){0.f,0.f,0.f,0.f};
    __syncthreads();

    #pragma unroll
    for (int kk = 0; kk < 12; ++kk) {
        bf16x8 af[4];
        #pragma unroll
        for (int ng = 0; ng < 4; ++ng) {
            int n = ng*16 + tx;
            int gs = (kk*4 + ty) ^ (n & 7);
            af[ng] = *reinterpret_cast<const bf16x8*>(xb + n*384 + gs*8);
        }
        #pragma unroll
        for (int cs = 0; cs < 3; ++cs) {
            int col = z*KC + wid*48 + cs*16 + tx;
            bf16x8 bf = *reinterpret_cast<const bf16x8*>(WT2 + ((size_t)kk*KC2 + col)*32 + ty*8);
            #pragma unroll
            for (int ng = 0; ng < 4; ++ng)
                acc[ng][cs] = MFMA_16x16x32(af[ng], bf, acc[ng][cs], 0, 0, 0);
        }
    }
    #pragma unroll
    for (int cs = 0; cs < 3; ++cs) {
        int col = z*KC + wid*48 + cs*16 + tx;
        float bv = bias[col];
        int w = col >> 5, tyq = (col >> 3) & 3, j = col & 7;
        #pragma unroll
        for (int ng = 0; ng < 4; ++ng) {
            int nt = nb*4 + ng;
            size_t base = ((((size_t)(b*256 + nt)*24 + w)*4 + tyq)*16)*8 + j;
            #pragma unroll
            for (int r = 0; r < 4; ++r) {
                int row = ty*4 + r;
                dstAf[base + (size_t)row*8] = f2bf(acc[ng][cs][r] + bv);
            }
        }
    }
}

// ---------------- K5: k_out5 (branch A): wave-owns-n-quarter QK^T, dbuf p, 1 barrier/iter
// LDS: p0 [64][140] @0 (17920); p1 @17920 (17920); total 35840
__global__ __launch_bounds__(512, 4) void k_out5(
    const unsigned short* __restrict__ QAf, const unsigned short* __restrict__ KA,
    const float* __restrict__ ba, const unsigned short* __restrict__ Mt2,
    const float* __restrict__ bproj, float* __restrict__ out)
{
    extern __shared__ char smem[];
    unsigned short* p0 = (unsigned short*)smem;
    unsigned short* p1 = (unsigned short*)(smem + 17920);

    const int tid = threadIdx.x;
    const int wid = tid >> 6, lane = tid & 63;
    const int tx = lane & 15, ty = lane >> 4;
    const int nb = blockIdx.x, b = blockIdx.y;
    const int hq2 = wid >> 2, wn = wid & 3;   // QK^T: head-of-pair, n-quarter
    const int es = wid * 48;                  // PV: e-slice
    const float ba0 = ba[0];

    f32x4 oacc[4][3];
    #pragma unroll
    for (int i = 0; i < 4; ++i)
        #pragma unroll
        for (int j = 0; j < 3; ++j) oacc[i][j] = (f32x4){0.f,0.f,0.f,0.f};

    for (int it = 0; it < 6; ++it) {
        unsigned short* pb = (it & 1) ? p1 : p0;
        const int hq = it*2 + hq2;
        // ---- QK^T: wave computes [16 n][64 m]; 4 m-slice B-frags x 2 branches
        const unsigned short* ap = QAf +
            (((size_t)(b*256 + nb*4 + wn)*24 + hq))*512 + (size_t)lane*8;
        bf16x8 a0 = *reinterpret_cast<const bf16x8*>(ap);
        bf16x8 a1 = *reinterpret_cast<const bf16x8*>(ap + 12*512);
        f32x4 tacc[4];
        #pragma unroll
        for (int s = 0; s < 4; ++s) tacc[s] = (f32x4){0.f,0.f,0.f,0.f};
        __builtin_amdgcn_s_setprio(1);
        #pragma unroll
        for (int s = 0; s < 4; ++s) {
            bf16x8 kb0 = *reinterpret_cast<const bf16x8*>(
                KA + ((size_t)(b*24 + hq)*64 + s*16 + tx)*32 + ty*8);
            bf16x8 kb1 = *reinterpret_cast<const bf16x8*>(
                KA + ((size_t)(b*24 + 12 + hq)*64 + s*16 + tx)*32 + ty*8);
            tacc[s] = MFMA_16x16x32(a0, kb0, tacc[s], 0, 0, 0);
            tacc[s] = MFMA_16x16x32(a1, kb1, tacc[s], 0, 0, 0);
        }
        __builtin_amdgcn_s_setprio(0);
        // ---- exp + in-wave row-sum over all 64 m (4 slices + tx-butterfly)
        float e[4][4];
        float ls[4] = {0.f, 0.f, 0.f, 0.f};
        #pragma unroll
        for (int s = 0; s < 4; ++s)
            #pragma unroll
            for (int r = 0; r < 4; ++r) {
                e[s][r] = __expf(tacc[s][r] + ba0);
                ls[r] += e[s][r];
            }
        #pragma unroll
        for (int mask = 1; mask < 16; mask <<= 1)
            #pragma unroll
            for (int r = 0; r < 4; ++r)
                ls[r] += __shfl_xor(ls[r], mask);
        float inv[4];
        #pragma unroll
        for (int r = 0; r < 4; ++r) inv[r] = 1.f / ls[r];
        // ---- write normalized P bf16 into pb[n][hq2*64 + s*16 + tx]
        #pragma unroll
        for (int s = 0; s < 4; ++s)
            #pragma unroll
            for (int r = 0; r < 4; ++r) {
                int n = wn*16 + ty*4 + r;
                pb[n*140 + hq2*64 + s*16 + tx] = f2bf(e[s][r] * inv[r]);
            }
        __syncthreads();   // pb visible everywhere; prev-iter PV (other buffer) unharmed
        // ---- PV: oacc += P[64 n][128 k] @ M2[128 k][48 e-slice]
        __builtin_amdgcn_s_setprio(1);
        #pragma unroll
        for (int ks = 0; ks < 4; ++ks) {
            const int hM = it*2 + (ks >> 1);
            const int inner = ks & 1;
            bf16x8 pa[4];
            #pragma unroll
            for (int ng = 0; ng < 4; ++ng)
                pa[ng] = *reinterpret_cast<const bf16x8*>(
                    pb + (ng*16 + tx)*140 + ks*32 + ty*8);
            #pragma unroll
            for (int j = 0; j < 3; ++j) {
                bf16x8 mf = *reinterpret_cast<const bf16x8*>(
                    Mt2 + (((size_t)(b*KH + hM)*2 + inner)*KC + es + j*16 + tx)*32 + ty*8);
                #pragma unroll
                for (int ng = 0; ng < 4; ++ng)
                    oacc[ng][j] = MFMA_16x16x32(pa[ng], mf, oacc[ng][j], 0, 0, 0);
            }
        }
        __builtin_amdgcn_s_setprio(0);
    }
    // epilogue
    float bp[3];
    #pragma unroll
    for (int j = 0; j < 3; ++j) bp[j] = bproj[es + j*16 + tx];
    #pragma unroll
    for (int ng = 0; ng < 4; ++ng)
        #pragma unroll
        for (int r = 0; r < 4; ++r) {
            size_t base = (size_t)(b*KN + nb*64 + ng*16 + ty*4 + r)*KC;
            #pragma unroll
            for (int j = 0; j < 3; ++j)
                out[base + es + j*16 + tx] = oacc[ng][j][r] + bp[j];
        }
}

extern "C" void kernel_launch(void* const* d_in, const int* in_sizes, int n_in,
                              void* d_out, int out_size, void* d_ws, size_t ws_size,
                              hipStream_t stream) {
    const float* x     = (const float*)d_in[0];
    const float* attn  = (const float*)d_in[1];
    const float* agent = (const float*)d_in[2];
    const float* Wq_lf = (const float*)d_in[3];
    const float* bq_lf = (const float*)d_in[4];
    const float* Wk_ag = (const float*)d_in[5];
    const float* bk_ag = (const float*)d_in[6];
    const float* wa    = (const float*)d_in[7];
    const float* ba    = (const float*)d_in[8];
    const float* Wq_ag = (const float*)d_in[9];
    const float* bq_ag = (const float*)d_in[10];
    const float* Wk_hf = (const float*)d_in[11];
    const float* bk_hf = (const float*)d_in[12];
    const float* Wv_hf = (const float*)d_in[13];
    const float* bv_hf = (const float*)d_in[14];
    const float* wb    = (const float*)d_in[15];
    const float* bb    = (const float*)d_in[16];
    const float* Wproj = (const float*)d_in[17];
    const float* bproj = (const float*)d_in[18];
    float* out = (float*)d_out;
    float* ws  = (float*)d_ws;

    // workspace layout (f32 units) — same proven footprint as round 9
    const size_t o_Kag  = 0;          // 393216
    const size_t o_Qa   = 393216;     // 393216
    const size_t o_cB   = 792576;     // 6144
    const size_t o_Fbf  = 798720;     // 1179648
    const size_t o_WkT  = 1978368;    // 294912
    const size_t o_WvT2 = 2273280;    // 36864
    const size_t o_WqT2 = 2310144;    // 147456
    const size_t o_KA   = 2457600;    // 196608
    const size_t o_Mt2  = 2654208;    // 1179648
    const size_t o_Abf  = 3833856;    // 3145728 (dead after flash3)
    const size_t o_Vt2  = 6979584;    // 6291456 (dead after flash3)
    const size_t o_lp   = 13271040;   // 196608 (nchunk=32)
    const size_t o_Vp   = 13467648;   // 6291456
    const size_t o_QAf  = 3833856;    // overlays dead flash region
    const int nchunk = 32;
    (void)ws_size; (void)in_sizes; (void)n_in; (void)out_size;

    unsigned short* Fbf  = (unsigned short*)(ws + o_Fbf);
    unsigned short* WvT2 = (unsigned short*)(ws + o_WvT2);
    unsigned short* WqT2 = (unsigned short*)(ws + o_WqT2);
    unsigned short* KA   = (unsigned short*)(ws + o_KA);
    unsigned short* Mt2  = (unsigned short*)(ws + o_Mt2);
    unsigned short* Abf  = (unsigned short*)(ws + o_Abf);
    unsigned short* Vt2  = (unsigned short*)(ws + o_Vt2);
    unsigned short* QAf  = (unsigned short*)(ws + o_QAf);

    k_agent_proj<<<dim3(64, 2), 256, 0, stream>>>(agent, Wk_ag, bk_ag, Wq_ag, bq_ag,
                                                  ws + o_Kag, ws + o_Qa);
    k_transpose<<<dim3(24, 12), dim3(32, 8), 0, stream>>>(Wk_hf, ws + o_WkT);
    // Wq_lf [384][768] -> WqT2 frag-major
    k_tcastT<<<dim3(6, 12, 1), 256, 0, stream>>>(Wq_lf, WqT2, nullptr,
                                                 KC, KC2, 0, 0, 0);
    // Wv [384][384] -> WvT2 frag-major
    k_tcastT<<<dim3(6, 6, 1), 256, 0, stream>>>(Wv_hf, WvT2, nullptr,
                                                 KC, KC, 0, 0, 0);
    k_kabc<<<dim3(KB), 256, 0, stream>>>(ws + o_Kag, ws + o_Qa, wa, bk_hf, wb, bb,
                                         KA, ws + o_cB);
    k_build_F<<<dim3(96, 8), 128, 0, stream>>>(ws + o_WkT, ws + o_Qa, wb, Fbf);

    const int vp_lds = 49152;
    const int fl_lds = 58880;
    const int qp_lds = 49152;
    const int ko_lds = 35840;
    (void)hipFuncSetAttribute(reinterpret_cast<const void*>(k_vproj2),
                              hipFuncAttributeMaxDynamicSharedMemorySize, vp_lds);
    (void)hipFuncSetAttribute(reinterpret_cast<const void*>(k_flash3),
                              hipFuncAttributeMaxDynamicSharedMemorySize, fl_lds);
    (void)hipFuncSetAttribute(reinterpret_cast<const void*>(k_qkproj),
                              hipFuncAttributeMaxDynamicSharedMemorySize, qp_lds);
    (void)hipFuncSetAttribute(reinterpret_cast<const void*>(k_out5),
                              hipFuncAttributeMaxDynamicSharedMemorySize, ko_lds);

    // V = attn @ Wv + bv  (also emits Abf = swizzled bf16 attn)
    k_vproj2<<<dim3(KN/64, KB), 512, vp_lds, stream>>>(attn, WvT2, bv_hf, Abf, Vt2);

    const int g_per = KB * nchunk;   // 256
    k_flash3<<<dim3(KH * g_per), 512, fl_lds, stream>>>(
        Abf, Vt2, Fbf, ws + o_cB, ws + o_Vp, ws + o_lp, nchunk, KN / nchunk, g_per);
    k_combine3<<<dim3(KH, KB), 384, 0, stream>>>(
        ws + o_Vp, ws + o_lp, Wproj, Mt2, nchunk);
    // Q = x @ Wq_lf + bq -> QAf (overlays dead flash-region)
    k_qkproj<<<dim3(KN/64, KB, 2), 512, qp_lds, stream>>>(x, WqT2, bq_lf, QAf);
    k_out5<<<dim3(KN/64, KB), 512, ko_lds, stream>>>(
        QAf, KA, ba, Mt2, bproj, out);
}

// Round 11
// 258.902 us; speedup vs baseline: 1.7319x; 1.3622x over previous
//
#include <hip/hip_runtime.h>

#define KB 8
#define KN 4096
#define KNA 64
#define KH 12
#define KD 32
#define KC 384
#define KC2 768
#define KSCALE 0.17677669529663688f
#define NCH 16

typedef __bf16 bf16x8 __attribute__((ext_vector_type(8)));
typedef float  f32x4  __attribute__((ext_vector_type(4)));

static __device__ __forceinline__ unsigned short f2bf(float f) {
    unsigned int u = __builtin_bit_cast(unsigned int, f);
    u += 0x7FFFu + ((u >> 16) & 1u);
    return (unsigned short)(u >> 16);
}
static __device__ __forceinline__ float bf2f(unsigned short h) {
    return __builtin_bit_cast(float, (unsigned int)h << 16);
}

static __device__ __forceinline__ void gld_lds16(const unsigned short* g, unsigned short* l) {
    __builtin_amdgcn_global_load_lds(
        (const __attribute__((address_space(1))) unsigned int*)g,
        (__attribute__((address_space(3))) unsigned int*)l, 16, 0, 0);
}

#define MFMA_16x16x32 __builtin_amdgcn_mfma_f32_16x16x32_bf16

// ---------------- transpose Wk_hf [384,768] -> WkT [768,384] (f32)
__global__ __launch_bounds__(256) void k_transpose(
    const float* __restrict__ Win, float* __restrict__ Wout)
{
    __shared__ float tile[32][33];
    const int tx = threadIdx.x, ty = threadIdx.y;
    const int j0 = blockIdx.x * 32, c0 = blockIdx.y * 32;
    #pragma unroll
    for (int yy = 0; yy < 4; ++yy)
        tile[ty + yy*8][tx] = Win[(size_t)(c0 + ty + yy*8)*KC2 + j0 + tx];
    __syncthreads();
    #pragma unroll
    for (int yy = 0; yy < 4; ++yy)
        Wout[(size_t)(j0 + ty + yy*8)*KC + c0 + tx] = tile[tx][ty + yy*8];
}

// ---------------- tcastT: src f32 [R][C] -> dstT bf16 frag-major [(r>>5)][C][32]
__global__ __launch_bounds__(256) void k_tcastT(
    const float* __restrict__ src, unsigned short* __restrict__ dstT,
    unsigned short* __restrict__ dstRM,
    int R, int C, long sstride, long dTstride, long dRMstride)
{
    __shared__ unsigned short lds[64][80];
    const int t = threadIdx.x;
    const int r0 = blockIdx.x * 64, c0 = blockIdx.y * 64;
    const float* s = src + (size_t)blockIdx.z * sstride;
    #pragma unroll
    for (int i = 0; i < 16; ++i) {
        int f = t + i*256; int rr = f >> 6, cc = f & 63;
        lds[rr][cc] = f2bf(s[(size_t)(r0+rr)*C + c0 + cc]);
    }
    __syncthreads();
    if (dstT) {
        unsigned short* dT = dstT + (size_t)blockIdx.z * dTstride;
        #pragma unroll
        for (int i = 0; i < 8; ++i) {
            int o = t + i*256;
            int chunk = o >> 10, c = (o >> 4) & 63, pair = o & 15;
            int r = chunk*32 + pair*2;
            unsigned int v = (unsigned int)lds[r][c] | ((unsigned int)lds[r+1][c] << 16);
            size_t off = ((size_t)((r0>>5) + chunk)*C + c0 + c)*32 + pair*2;
            *reinterpret_cast<unsigned int*>(dT + off) = v;
        }
    }
    if (dstRM) {
        unsigned short* dR = dstRM + (size_t)blockIdx.z * dRMstride;
        #pragma unroll
        for (int i = 0; i < 2; ++i) {
            int idx = t*2 + i;
            int n = idx >> 3, gt = idx & 7;
            int g = (c0 >> 3) + gt;
            int slot = g ^ ((r0 + n) & 7);
            *reinterpret_cast<bf16x8*>(dR + (size_t)(r0+n)*C + slot*8) =
                *reinterpret_cast<const bf16x8*>(&lds[n][gt*8]);
        }
    }
}

// ---------------- tcastHL: src f32 [384][768] -> hi/lo bf16 frag-major [12][768][32]
__global__ __launch_bounds__(256) void k_tcastHL(
    const float* __restrict__ src, unsigned short* __restrict__ dstHi,
    unsigned short* __restrict__ dstLo)
{
    __shared__ unsigned short lh[64][80];
    __shared__ unsigned short ll[64][80];
    const int t = threadIdx.x;
    const int r0 = blockIdx.x * 64, c0 = blockIdx.y * 64;
    #pragma unroll
    for (int i = 0; i < 16; ++i) {
        int f = t + i*256; int rr = f >> 6, cc = f & 63;
        float v = src[(size_t)(r0+rr)*KC2 + c0 + cc];
        unsigned short h = f2bf(v);
        lh[rr][cc] = h;
        ll[rr][cc] = f2bf(v - bf2f(h));
    }
    __syncthreads();
    #pragma unroll
    for (int i = 0; i < 8; ++i) {
        int o = t + i*256;
        int chunk = o >> 10, c = (o >> 4) & 63, pair = o & 15;
        int r = chunk*32 + pair*2;
        unsigned int vh = (unsigned int)lh[r][c] | ((unsigned int)lh[r+1][c] << 16);
        unsigned int vl = (unsigned int)ll[r][c] | ((unsigned int)ll[r+1][c] << 16);
        size_t off = ((size_t)((r0>>5) + chunk)*KC2 + c0 + c)*32 + pair*2;
        *reinterpret_cast<unsigned int*>(dstHi + off) = vh;
        *reinterpret_cast<unsigned int*>(dstLo + off) = vl;
    }
}

// ---------------- k_agproj2: Kag/Qa = agent @ W + bias via bf16 hi/lo-split MFMA (~f32 acc)
// grid (8 rowtiles, 2 wsel, 2 colhalf); LDS: aHi [64][384] + aLo = 98304 B
__global__ __launch_bounds__(512, 1) void k_agproj2(
    const float* __restrict__ agent,
    const unsigned short* __restrict__ KHi, const unsigned short* __restrict__ KLo,
    const unsigned short* __restrict__ QHi, const unsigned short* __restrict__ QLo,
    const float* __restrict__ bk_ag, const float* __restrict__ bq_ag,
    float* __restrict__ Kag, float* __restrict__ Qa)
{
    extern __shared__ char smem[];
    unsigned short* aHi = (unsigned short*)smem;
    unsigned short* aLo = (unsigned short*)(smem + 49152);
    const int tid = threadIdx.x;
    const int wid = tid >> 6, lane = tid & 63;
    const int tx = lane & 15, ty = lane >> 4;
    const int rt = blockIdx.x, wsel = blockIdx.y, z = blockIdx.z;
    const unsigned short* WHi = wsel ? QHi : KHi;
    const unsigned short* WLo = wsel ? QLo : KLo;
    const float* bias = wsel ? bq_ag : bk_ag;
    float* dst = wsel ? Qa : Kag;

    {   // stage agent rows rt*64..+63 as hi/lo swizzled bf16
        const float4* s4 = reinterpret_cast<const float4*>(agent + (size_t)rt*64*KC);
        #pragma unroll
        for (int i = 0; i < 12; ++i) {
            int f = tid + i*512;
            int n = f / 96, c4 = f % 96;
            float4 v = s4[f];
            ushort4 h4, l4;
            h4.x = f2bf(v.x); l4.x = f2bf(v.x - bf2f(h4.x));
            h4.y = f2bf(v.y); l4.y = f2bf(v.y - bf2f(h4.y));
            h4.z = f2bf(v.z); l4.z = f2bf(v.z - bf2f(h4.z));
            h4.w = f2bf(v.w); l4.w = f2bf(v.w - bf2f(h4.w));
            int g = c4 >> 1, half = c4 & 1;
            int gs = g ^ (n & 7);
            *reinterpret_cast<ushort4*>(aHi + n*384 + gs*8 + half*4) = h4;
            *reinterpret_cast<ushort4*>(aLo + n*384 + gs*8 + half*4) = l4;
        }
    }
    f32x4 acc[4][3];
    #pragma unroll
    for (int i = 0; i < 4; ++i)
        #pragma unroll
        for (int j = 0; j < 3; ++j) acc[i][j] = (f32x4){0.f,0.f,0.f,0.f};
    __syncthreads();

    #pragma unroll
    for (int kk = 0; kk < 12; ++kk) {
        bf16x8 ah[4], al[4];
        #pragma unroll
        for (int ng = 0; ng < 4; ++ng) {
            int n = ng*16 + tx;
            int gs = (kk*4 + ty) ^ (n & 7);
            ah[ng] = *reinterpret_cast<const bf16x8*>(aHi + n*384 + gs*8);
            al[ng] = *reinterpret_cast<const bf16x8*>(aLo + n*384 + gs*8);
        }
        #pragma unroll
        for (int cs = 0; cs < 3; ++cs) {
            int col = z*KC + wid*48 + cs*16 + tx;
            bf16x8 bh = *reinterpret_cast<const bf16x8*>(WHi + ((size_t)kk*KC2 + col)*32 + ty*8);
            bf16x8 bl = *reinterpret_cast<const bf16x8*>(WLo + ((size_t)kk*KC2 + col)*32 + ty*8);
            #pragma unroll
            for (int ng = 0; ng < 4; ++ng) {
                acc[ng][cs] = MFMA_16x16x32(ah[ng], bh, acc[ng][cs], 0, 0, 0);
                acc[ng][cs] = MFMA_16x16x32(ah[ng], bl, acc[ng][cs], 0, 0, 0);
                acc[ng][cs] = MFMA_16x16x32(al[ng], bh, acc[ng][cs], 0, 0, 0);
            }
        }
    }
    #pragma unroll
    for (int cs = 0; cs < 3; ++cs) {
        int col = z*KC + wid*48 + cs*16 + tx;
        float bv = bias[col];
        #pragma unroll
        for (int ng = 0; ng < 4; ++ng)
            #pragma unroll
            for (int r = 0; r < 4; ++r) {
                int row = rt*64 + ng*16 + ty*4 + r;
                dst[(size_t)row*KC2 + col] = acc[ng][cs][r] + bv;
            }
    }
}

// ---------------- K2b: F_bf[b][hm][c] bf16 row-major (branch-B scores)
__global__ __launch_bounds__(128) void k_build_F(
    const float* __restrict__ WkT, const float* __restrict__ Qa,
    const float* __restrict__ wb, unsigned short* __restrict__ Fbf)
{
    __shared__ float q_lds[8][64];
    const int tid = threadIdx.x;
    const int g = blockIdx.x;
    const int b = blockIdx.y;
    const int h = (g*8) >> 6;
    const float t0 = KSCALE*wb[0], t1 = KSCALE*wb[1];
    #pragma unroll
    for (int l = 0; l < 4; ++l) {
        int v = tid + l*128;
        int i = v >> 6, d = v & 63;
        int m = (g*8 + i) & 63;
        int jj   = (d < KD) ? (h*KD + d) : (KC + h*KD + d - KD);
        float cf = (d < KD) ? t0 : t1;
        q_lds[i][d] = cf * Qa[(size_t)(b*KNA + m)*KC2 + jj];
    }
    __syncthreads();
    float acc[8][3] = {};
    for (int d = 0; d < 64; ++d) {
        int row = (d < KD) ? (h*KD + d) : (KC + h*KD + d - KD);
        const float* wr = WkT + (size_t)row*KC;
        float w0 = wr[tid], w1 = wr[tid+128], w2 = wr[tid+256];
        #pragma unroll
        for (int i = 0; i < 8; ++i) {
            float q = q_lds[i][d];
            acc[i][0] = fmaf(q, w0, acc[i][0]);
            acc[i][1] = fmaf(q, w1, acc[i][1]);
            acc[i][2] = fmaf(q, w2, acc[i][2]);
        }
    }
    #pragma unroll
    for (int i = 0; i < 8; ++i)
        #pragma unroll
        for (int l = 0; l < 3; ++l)
            Fbf[((size_t)b*KC2 + g*8 + i)*KC + tid + l*128] = f2bf(acc[i][l]);
}

// ---------------- k_kabc: KA (scaled K bf16 frag-major) + cB bias constants
__global__ __launch_bounds__(256) void k_kabc(
    const float* __restrict__ Kag, const float* __restrict__ Qa,
    const float* __restrict__ wa, const float* __restrict__ bk_hf,
    const float* __restrict__ wb, const float* __restrict__ bbv,
    unsigned short* __restrict__ KA, float* __restrict__ cB)
{
    const int b = blockIdx.x, tid = threadIdx.x;
    const float s0 = KSCALE * wa[0], s1 = KSCALE * wa[1];
    #pragma unroll
    for (int i = 0; i < 24; ++i) {
        int v = tid + i*256;
        int w = v >> 8, m = (v >> 2) & 63, k8 = v & 3;
        float sc = (w >= 12) ? s1 : s0;
        const float* sp = Kag + ((size_t)(b*KNA + m))*KC2 + w*32 + k8*8;
        float4 f0 = *reinterpret_cast<const float4*>(sp);
        float4 f1 = *reinterpret_cast<const float4*>(sp + 4);
        ushort4 h0 = { f2bf(f0.x*sc), f2bf(f0.y*sc), f2bf(f0.z*sc), f2bf(f0.w*sc) };
        ushort4 h1 = { f2bf(f1.x*sc), f2bf(f1.y*sc), f2bf(f1.z*sc), f2bf(f1.w*sc) };
        unsigned short* dp = KA + ((size_t)(b*24 + w)*64 + m)*32 + k8*8;
        *reinterpret_cast<ushort4*>(dp)     = h0;
        *reinterpret_cast<ushort4*>(dp + 4) = h1;
    }
    const float t0 = KSCALE*wb[0], t1 = KSCALE*wb[1];
    for (int hm = tid; hm < KC2; hm += 256) {
        int h = hm >> 6, m = hm & 63;
        const float* qp = Qa + (size_t)(b*KNA + m)*KC2;
        float bb2 = 0.f;
        for (int d = 0; d < KD; ++d)
            bb2 += t0*bk_hf[h*KD+d]*qp[h*KD+d] + t1*bk_hf[KC+h*KD+d]*qp[KC+h*KD+d];
        cB[(size_t)b*KC2 + hm] = bb2 + bbv[0];
    }
}

// ---------------- k_vproj2: reads attn f32; writes Abf (swizzled bf16) + Vt2 (frag-major)
__global__ __launch_bounds__(512, 4) void k_vproj2(
    const float* __restrict__ attn, const unsigned short* __restrict__ WvT2,
    const float* __restrict__ bv, unsigned short* __restrict__ Abf,
    unsigned short* __restrict__ Vt2)
{
    extern __shared__ char smem[];
    unsigned short* a_rm = (unsigned short*)smem;   // 49152B
    const int tid = threadIdx.x;
    const int wid = tid >> 6, lane = tid & 63;
    const int tx = lane & 15, ty = lane >> 4;
    const int nb = blockIdx.x, b = blockIdx.y;
    const int wn = wid >> 2, wd = wid & 3;

    {
        const float4* src = reinterpret_cast<const float4*>(attn + ((size_t)(b*KN + nb*64))*KC);
        unsigned short* ab = Abf + ((size_t)(b*KN + nb*64))*KC;
        #pragma unroll
        for (int i = 0; i < 12; ++i) {
            int f = tid + i*512;
            int n = f / 96, c4 = f % 96;
            float4 v = src[f];
            ushort4 h4 = { f2bf(v.x), f2bf(v.y), f2bf(v.z), f2bf(v.w) };
            int g = c4 >> 1, half = c4 & 1;
            int gs = g ^ (n & 7);
            *reinterpret_cast<ushort4*>(a_rm + n*384 + gs*8 + half*4) = h4;
            *reinterpret_cast<ushort4*>(ab + (size_t)n*384 + gs*8 + half*4) = h4;
        }
    }
    f32x4 acc[2][6];
    #pragma unroll
    for (int i = 0; i < 2; ++i)
        #pragma unroll
        for (int j = 0; j < 6; ++j) acc[i][j] = (f32x4){0.f,0.f,0.f,0.f};
    __syncthreads();

    #pragma unroll
    for (int kk = 0; kk < 12; ++kk) {
        bf16x8 af[2];
        #pragma unroll
        for (int ns = 0; ns < 2; ++ns) {
            int n = wn*32 + ns*16 + tx;
            int gs = (kk*4 + ty) ^ (n & 7);
            af[ns] = *reinterpret_cast<const bf16x8*>(a_rm + n*384 + gs*8);
        }
        #pragma unroll
        for (int cs = 0; cs < 6; ++cs) {
            int d = wd*96 + cs*16 + tx;
            bf16x8 bf = *reinterpret_cast<const bf16x8*>(WvT2 + ((size_t)kk*KC + d)*32 + ty*8);
            #pragma unroll
            for (int ns = 0; ns < 2; ++ns)
                acc[ns][cs] = MFMA_16x16x32(af[ns], bf, acc[ns][cs], 0, 0, 0);
        }
    }
    #pragma unroll
    for (int cs = 0; cs < 6; ++cs) {
        int d = wd*96 + cs*16 + tx;
        float bvv = bv[d];
        #pragma unroll
        for (int ns = 0; ns < 2; ++ns) {
            ushort4 h4;
            h4.x = f2bf(acc[ns][cs][0] + bvv);
            h4.y = f2bf(acc[ns][cs][1] + bvv);
            h4.z = f2bf(acc[ns][cs][2] + bvv);
            h4.w = f2bf(acc[ns][cs][3] + bvv);
            size_t off = (((size_t)b*(KN>>5) + nb*2 + wn)*KC + d)*32 + ns*16 + ty*4;
            *reinterpret_cast<ushort4*>(Vt2 + off) = h4;
        }
    }
}

// ---------------- K3: V-form MFMA flash (branch B), 64-row tiles
__global__ __launch_bounds__(512, 4) void k_flash3(
    const unsigned short* __restrict__ Abf, const unsigned short* __restrict__ Vt2,
    const unsigned short* __restrict__ Fbf, const float* __restrict__ cB,
    float* __restrict__ Vpart, float* __restrict__ lpart,
    int nchunk, int NK, int g_per)
{
    extern __shared__ char smem[];
    unsigned short* a_rm = (unsigned short*)smem;
    unsigned short* p    = (unsigned short*)(smem + 49152);
    float*          redl = (float*)(smem + 58368);

    const int tid = threadIdx.x;
    const int wid = tid >> 6, lane = tid & 63;
    const int tx = lane & 15, ty = lane >> 4;
    const unsigned bid = blockIdx.x;
    const int h = bid / g_per;
    const unsigned g = bid - h*g_per;
    const int b = g / nchunk;
    const int chunk = g - b*nchunk;
    const int n0 = chunk * NK;
    const int wn = wid >> 2, wh = wid & 3;
    const int wph = wid >> 1, wpd = wid & 1;

    bf16x8 ffrag[12];
    {
        const unsigned short* fp = Fbf + ((size_t)(b*KC2 + h*64 + wh*16 + tx))*KC + ty*8;
        #pragma unroll
        for (int kk = 0; kk < 12; ++kk)
            ffrag[kk] = *reinterpret_cast<const bf16x8*>(fp + kk*32);
    }
    const float cbv = cB[(size_t)b*KC2 + h*64 + wh*16 + tx];
    float lacc = 0.f;
    f32x4 Vacc = (f32x4){0.f,0.f,0.f,0.f};

    const unsigned short* atile = Abf + ((size_t)b*KN + n0)*KC;
    #pragma unroll
    for (int i = 0; i < 6; ++i)
        gld_lds16(atile + (size_t)tid*8 + i*4096, a_rm + tid*8 + i*4096);
    __syncthreads();

    const int NT = NK >> 6;
    for (int nt = 0; nt < NT; ++nt) {
        size_t vrow = (size_t)b*(KN >> 5) + ((n0 + nt*64) >> 5);
        bf16x8 vf0 = *reinterpret_cast<const bf16x8*>(
            Vt2 + ((vrow + 0)*KC + h*KD + wpd*16 + tx)*32 + ty*8);
        bf16x8 vf1 = *reinterpret_cast<const bf16x8*>(
            Vt2 + ((vrow + 1)*KC + h*KD + wpd*16 + tx)*32 + ty*8);
        f32x4 tacc[2];
        tacc[0] = (f32x4){0.f,0.f,0.f,0.f};
        tacc[1] = (f32x4){0.f,0.f,0.f,0.f};
        __builtin_amdgcn_s_setprio(1);
        #pragma unroll
        for (int kk = 0; kk < 12; ++kk) {
            #pragma unroll
            for (int ns = 0; ns < 2; ++ns) {
                int n = wn*32 + ns*16 + tx;
                int gs = (kk*4 + ty) ^ (n & 7);
                bf16x8 af = *reinterpret_cast<const bf16x8*>(a_rm + n*384 + gs*8);
                tacc[ns] = MFMA_16x16x32(af, ffrag[kk], tacc[ns], 0, 0, 0);
            }
        }
        __builtin_amdgcn_s_setprio(0);
        #pragma unroll
        for (int ns = 0; ns < 2; ++ns) {
            float e0 = __expf(tacc[ns][0] + cbv);
            float e1 = __expf(tacc[ns][1] + cbv);
            float e2 = __expf(tacc[ns][2] + cbv);
            float e3 = __expf(tacc[ns][3] + cbv);
            lacc += e0 + e1 + e2 + e3;
            int hm = wh*16 + tx;
            int np = wn*32 + ns*16 + ty*4;
            ushort4 h4 = { f2bf(e0), f2bf(e1), f2bf(e2), f2bf(e3) };
            *reinterpret_cast<ushort4*>(p + hm*72 + np) = h4;
        }
        __syncthreads();
        if (nt + 1 < NT) {
            const unsigned short* at = atile + (size_t)(nt+1)*64*KC;
            #pragma unroll
            for (int i = 0; i < 6; ++i)
                gld_lds16(at + (size_t)tid*8 + i*4096, a_rm + tid*8 + i*4096);
        }
        bf16x8 pa0 = *reinterpret_cast<const bf16x8*>(p + (wph*16 + tx)*72 + 0*32 + ty*8);
        bf16x8 pa1 = *reinterpret_cast<const bf16x8*>(p + (wph*16 + tx)*72 + 1*32 + ty*8);
        Vacc = MFMA_16x16x32(pa0, vf0, Vacc, 0, 0, 0);
        Vacc = MFMA_16x16x32(pa1, vf1, Vacc, 0, 0, 0);
        __syncthreads();
    }
    #pragma unroll
    for (int r = 0; r < 4; ++r)
        Vpart[(((size_t)(b*KH + h)*nchunk + chunk)*64 + wph*16 + ty*4 + r)*32 + wpd*16 + tx]
            = Vacc[r];
    lacc += __shfl_xor(lacc, 16);
    lacc += __shfl_xor(lacc, 32);
    if (lane < 16) redl[wn*64 + wh*16 + tx] = lacc;
    __syncthreads();
    if (tid < 64)
        lpart[((size_t)b*KC2 + h*64 + tid)*nchunk + chunk] = redl[tid] + redl[64 + tid];
}

// ---------------- K4: combine4: per (h,b,hm-quarter): x_s -> Mt2 bf16 frag-major
__global__ __launch_bounds__(384) void k_combine4(
    const float* __restrict__ Vpart, const float* __restrict__ lpart,
    const float* __restrict__ Wproj, unsigned short* __restrict__ Mt2)
{
    __shared__ float xs[16][32];
    __shared__ float lred[16][NCH];
    __shared__ float invl[16];
    const int h = blockIdx.x, b = blockIdx.y, q = blockIdx.z;
    const int tid = threadIdx.x;   // 384
    if (tid < 16*NCH) {
        int hm_l = tid >> 4, ch = tid & (NCH-1);
        lred[hm_l][ch] = lpart[((size_t)b*KC2 + h*64 + q*16 + hm_l)*NCH + ch];
    }
    __syncthreads();
    if (tid < 16) {
        float s = 0.f;
        #pragma unroll
        for (int j = 0; j < NCH; ++j) s += lred[tid][j];
        invl[tid] = 1.f / s;
    }
    __syncthreads();
    for (int v = tid; v < 512; v += 384) {
        int hm_l = v >> 5, d = v & 31;
        const float* vp = Vpart + (((size_t)(b*KH + h)*NCH)*64 + q*16 + hm_l)*32 + d;
        float u = 0.f;
        #pragma unroll
        for (int ch = 0; ch < NCH; ++ch) u += vp[(size_t)ch*2048];
        xs[hm_l][d] = u * invl[hm_l];
    }
    __syncthreads();
    const int e = tid;
    float wp[32];
    #pragma unroll
    for (int d = 0; d < 32; ++d) wp[d] = Wproj[(size_t)(h*KD + d)*KC + e];
    ushort4 line[4];
    #pragma unroll
    for (int mq = 0; mq < 4; ++mq) {
        float a4[4];
        #pragma unroll
        for (int mr = 0; mr < 4; ++mr) {
            float a = 0.f;
            #pragma unroll
            for (int d = 0; d < 32; ++d)
                a = fmaf(xs[mq*4 + mr][d], wp[d], a);
            a4[mr] = a;
        }
        line[mq] = (ushort4){ f2bf(a4[0]), f2bf(a4[1]), f2bf(a4[2]), f2bf(a4[3]) };
    }
    unsigned short* dst = Mt2 + (((size_t)(b*KH + h)*2 + (q >> 1))*KC + e)*32 + (q & 1)*16;
    #pragma unroll
    for (int mq = 0; mq < 4; ++mq)
        *reinterpret_cast<ushort4*>(dst + mq*4) = line[mq];
}

// ---------------- k_qkproj: Q = src @ W + bias -> A-frag-major QAf
__global__ __launch_bounds__(512, 4) void k_qkproj(
    const float* __restrict__ src, const unsigned short* __restrict__ WT2,
    const float* __restrict__ bias, unsigned short* __restrict__ dstAf)
{
    extern __shared__ char smem[];
    unsigned short* xb = (unsigned short*)smem;
    const int tid = threadIdx.x;
    const int wid = tid >> 6, lane = tid & 63;
    const int tx = lane & 15, ty = lane >> 4;
    const int nb = blockIdx.x, b = blockIdx.y, z = blockIdx.z;

    {
        const float4* s4 = reinterpret_cast<const float4*>(src + ((size_t)(b*KN + nb*64))*KC);
        #pragma unroll
        for (int i = 0; i < 12; ++i) {
            int f = tid + i*512;
            int n = f / 96, c4 = f % 96;
            float4 v = s4[f];
            ushort4 h4 = { f2bf(v.x), f2bf(v.y), f2bf(v.z), f2bf(v.w) };
            int g = c4 >> 1, half = c4 & 1;
            int gs = g ^ (n & 7);
            *reinterpret_cast<ushort4*>(xb + n*384 + gs*8 + half*4) = h4;
        }
    }
    f32x4 acc[4][3];
    #pragma unroll
    for (int i = 0; i < 4; ++i)
        #pragma unroll
        for (int j = 0; j < 3; ++j) acc[i][j] = (f32x4){0.f,0.f,0.f,0.f};
    __syncthreads();

    #pragma unroll
    for (int kk = 0; kk < 12; ++kk) {
        bf16x8 af[4];
        #pragma unroll
        for (int ng = 0; ng < 4; ++ng) {
            int n = ng*16 + tx;
            int gs = (kk*4 + ty) ^ (n & 7);
            af[ng] = *reinterpret_cast<const bf16x8*>(xb + n*384 + gs*8);
        }
        #pragma unroll
        for (int cs = 0; cs < 3; ++cs) {
            int col = z*KC + wid*48 + cs*16 + tx;
            bf16x8 bf = *reinterpret_cast<const bf16x8*>(WT2 + ((size_t)kk*KC2 + col)*32 + ty*8);
            #pragma unroll
            for (int ng = 0; ng < 4; ++ng)
                acc[ng][cs] = MFMA_16x16x32(af[ng], bf, acc[ng][cs], 0, 0, 0);
        }
    }
    #pragma unroll
    for (int cs = 0; cs < 3; ++cs) {
        int col = z*KC + wid*48 + cs*16 + tx;
        float bv = bias[col];
        int w = col >> 5, tyq = (col >> 3) & 3, j = col & 7;
        #pragma unroll
        for (int ng = 0; ng < 4; ++ng) {
            int nt = nb*4 + ng;
            size_t base = ((((size_t)(b*256 + nt)*24 + w)*4 + tyq)*16)*8 + j;
            #pragma unroll
            for (int r = 0; r < 4; ++r) {
                int row = ty*4 + r;
                dstAf[base + (size_t)row*8] = f2bf(acc[ng][cs][r] + bv);
            }
        }
    }
}

// ---------------- K5: k_out5 (branch A): wave-owns-n-quarter QK^T, dbuf p, 1 barrier/iter
__global__ __launch_bounds__(512, 4) void k_out5(
    const unsigned short* __restrict__ QAf, const unsigned short* __restrict__ KA,
    const float* __restrict__ ba, const unsigned short* __restrict__ Mt2,
    const float* __restrict__ bproj, float* __restrict__ out)
{
    extern __shared__ char smem[];
    unsigned short* p0 = (unsigned short*)smem;
    unsigned short* p1 = (unsigned short*)(smem + 17920);

    const int tid = threadIdx.x;
    const int wid = tid >> 6, lane = tid & 63;
    const int tx = lane & 15, ty = lane >> 4;
    const int nb = blockIdx.x, b = blockIdx.y;
    const int hq2 = wid >> 2, wn = wid & 3;
    const int es = wid * 48;
    const float ba0 = ba[0];

    f32x4 oacc[4][3];
    #pragma unroll
    for (int i = 0; i < 4; ++i)
        #pragma unroll
        for (int j = 0; j < 3; ++j) oacc[i][j] = (f32x4){0.f,0.f,0.f,0.f};

    for (int it = 0; it < 6; ++it) {
        unsigned short* pb = (it & 1) ? p1 : p0;
        const int hq = it*2 + hq2;
        const unsigned short* ap = QAf +
            (((size_t)(b*256 + nb*4 + wn)*24 + hq))*512 + (size_t)lane*8;
        bf16x8 a0 = *reinterpret_cast<const bf16x8*>(ap);
        bf16x8 a1 = *reinterpret_cast<const bf16x8*>(ap + 12*512);
        f32x4 tacc[4];
        #pragma unroll
        for (int s = 0; s < 4; ++s) tacc[s] = (f32x4){0.f,0.f,0.f,0.f};
        __builtin_amdgcn_s_setprio(1);
        #pragma unroll
        for (int s = 0; s < 4; ++s) {
            bf16x8 kb0 = *reinterpret_cast<const bf16x8*>(
                KA + ((size_t)(b*24 + hq)*64 + s*16 + tx)*32 + ty*8);
            bf16x8 kb1 = *reinterpret_cast<const bf16x8*>(
                KA + ((size_t)(b*24 + 12 + hq)*64 + s*16 + tx)*32 + ty*8);
            tacc[s] = MFMA_16x16x32(a0, kb0, tacc[s], 0, 0, 0);
            tacc[s] = MFMA_16x16x32(a1, kb1, tacc[s], 0, 0, 0);
        }
        __builtin_amdgcn_s_setprio(0);
        float e[4][4];
        float ls[4] = {0.f, 0.f, 0.f, 0.f};
        #pragma unroll
        for (int s = 0; s < 4; ++s)
            #pragma unroll
            for (int r = 0; r < 4; ++r) {
                e[s][r] = __expf(tacc[s][r] + ba0);
                ls[r] += e[s][r];
            }
        #pragma unroll
        for (int mask = 1; mask < 16; mask <<= 1)
            #pragma unroll
            for (int r = 0; r < 4; ++r)
                ls[r] += __shfl_xor(ls[r], mask);
        float inv[4];
        #pragma unroll
        for (int r = 0; r < 4; ++r) inv[r] = 1.f / ls[r];
        #pragma unroll
        for (int s = 0; s < 4; ++s)
            #pragma unroll
            for (int r = 0; r < 4; ++r) {
                int n = wn*16 + ty*4 + r;
                pb[n*140 + hq2*64 + s*16 + tx] = f2bf(e[s][r] * inv[r]);
            }
        __syncthreads();
        __builtin_amdgcn_s_setprio(1);
        #pragma unroll
        for (int ks = 0; ks < 4; ++ks) {
            const int hM = it*2 + (ks >> 1);
            const int inner = ks & 1;
            bf16x8 pa[4];
            #pragma unroll
            for (int ng = 0; ng < 4; ++ng)
                pa[ng] = *reinterpret_cast<const bf16x8*>(
                    pb + (ng*16 + tx)*140 + ks*32 + ty*8);
            #pragma unroll
            for (int j = 0; j < 3; ++j) {
                bf16x8 mf = *reinterpret_cast<const bf16x8*>(
                    Mt2 + (((size_t)(b*KH + hM)*2 + inner)*KC + es + j*16 + tx)*32 + ty*8);
                #pragma unroll
                for (int ng = 0; ng < 4; ++ng)
                    oacc[ng][j] = MFMA_16x16x32(pa[ng], mf, oacc[ng][j], 0, 0, 0);
            }
        }
        __builtin_amdgcn_s_setprio(0);
    }
    float bp[3];
    #pragma unroll
    for (int j = 0; j < 3; ++j) bp[j] = bproj[es + j*16 + tx];
    #pragma unroll
    for (int ng = 0; ng < 4; ++ng)
        #pragma unroll
        for (int r = 0; r < 4; ++r) {
            size_t base = (size_t)(b*KN + nb*64 + ng*16 + ty*4 + r)*KC;
            #pragma unroll
            for (int j = 0; j < 3; ++j)
                out[base + es + j*16 + tx] = oacc[ng][j][r] + bp[j];
        }
}

extern "C" void kernel_launch(void* const* d_in, const int* in_sizes, int n_in,
                              void* d_out, int out_size, void* d_ws, size_t ws_size,
                              hipStream_t stream) {
    const float* x     = (const float*)d_in[0];
    const float* attn  = (const float*)d_in[1];
    const float* agent = (const float*)d_in[2];
    const float* Wq_lf = (const float*)d_in[3];
    const float* bq_lf = (const float*)d_in[4];
    const float* Wk_ag = (const float*)d_in[5];
    const float* bk_ag = (const float*)d_in[6];
    const float* wa    = (const float*)d_in[7];
    const float* ba    = (const float*)d_in[8];
    const float* Wq_ag = (const float*)d_in[9];
    const float* bq_ag = (const float*)d_in[10];
    const float* Wk_hf = (const float*)d_in[11];
    const float* bk_hf = (const float*)d_in[12];
    const float* Wv_hf = (const float*)d_in[13];
    const float* bv_hf = (const float*)d_in[14];
    const float* wb    = (const float*)d_in[15];
    const float* bb    = (const float*)d_in[16];
    const float* Wproj = (const float*)d_in[17];
    const float* bproj = (const float*)d_in[18];
    float* out = (float*)d_out;
    float* ws  = (float*)d_ws;

    // workspace layout (f32 units) — footprint identical to rounds 9/10 (proven)
    const size_t o_Kag  = 0;          // 393216
    const size_t o_Qa   = 393216;     // 393216
    const size_t o_cB   = 792576;     // 6144
    const size_t o_Fbf  = 798720;     // 1179648
    const size_t o_WkT  = 1978368;    // 294912
    const size_t o_WvT2 = 2273280;    // 36864
    const size_t o_WqT2 = 2310144;    // 147456
    const size_t o_KA   = 2457600;    // 196608
    const size_t o_Mt2  = 2654208;    // 1179648
    const size_t o_Abf  = 3833856;    // 3145728 (dead after flash3)
    const size_t o_Vt2  = 6979584;    // 6291456 (dead after flash3)
    const size_t o_lp   = 13271040;   // slot 196608 (NCH=16 uses 98304)
    const size_t o_Vp   = 13467648;   // slot 6291456 (NCH=16 uses 3145728)
    const size_t o_QAf  = 3833856;    // overlays dead flash region
    // hi/lo agent weights live in the Abf slot until k_vproj2 overwrites it
    const size_t o_KHi  = o_Abf;               // 147456
    const size_t o_KLo  = o_Abf + 147456;      // 147456
    const size_t o_QHi  = o_Abf + 294912;      // 147456
    const size_t o_QLo  = o_Abf + 442368;      // 147456
    (void)ws_size; (void)in_sizes; (void)n_in; (void)out_size;

    unsigned short* Fbf  = (unsigned short*)(ws + o_Fbf);
    unsigned short* WvT2 = (unsigned short*)(ws + o_WvT2);
    unsigned short* WqT2 = (unsigned short*)(ws + o_WqT2);
    unsigned short* KA   = (unsigned short*)(ws + o_KA);
    unsigned short* Mt2  = (unsigned short*)(ws + o_Mt2);
    unsigned short* Abf  = (unsigned short*)(ws + o_Abf);
    unsigned short* Vt2  = (unsigned short*)(ws + o_Vt2);
    unsigned short* QAf  = (unsigned short*)(ws + o_QAf);
    unsigned short* KHi  = (unsigned short*)(ws + o_KHi);
    unsigned short* KLo  = (unsigned short*)(ws + o_KLo);
    unsigned short* QHi  = (unsigned short*)(ws + o_QHi);
    unsigned short* QLo  = (unsigned short*)(ws + o_QLo);

    const int ap_lds = 98304;
    const int vp_lds = 49152;
    const int fl_lds = 58880;
    const int qp_lds = 49152;
    const int ko_lds = 35840;
    (void)hipFuncSetAttribute(reinterpret_cast<const void*>(k_agproj2),
                              hipFuncAttributeMaxDynamicSharedMemorySize, ap_lds);
    (void)hipFuncSetAttribute(reinterpret_cast<const void*>(k_vproj2),
                              hipFuncAttributeMaxDynamicSharedMemorySize, vp_lds);
    (void)hipFuncSetAttribute(reinterpret_cast<const void*>(k_flash3),
                              hipFuncAttributeMaxDynamicSharedMemorySize, fl_lds);
    (void)hipFuncSetAttribute(reinterpret_cast<const void*>(k_qkproj),
                              hipFuncAttributeMaxDynamicSharedMemorySize, qp_lds);
    (void)hipFuncSetAttribute(reinterpret_cast<const void*>(k_out5),
                              hipFuncAttributeMaxDynamicSharedMemorySize, ko_lds);

    // hi/lo frag-major agent weights (in dead-until-vproj2 region)
    k_tcastHL<<<dim3(6, 12), 256, 0, stream>>>(Wk_ag, KHi, KLo);
    k_tcastHL<<<dim3(6, 12), 256, 0, stream>>>(Wq_ag, QHi, QLo);
    // Kag/Qa via hi/lo-split MFMA (~f32 accurate)
    k_agproj2<<<dim3(8, 2, 2), 512, ap_lds, stream>>>(
        agent, KHi, KLo, QHi, QLo, bk_ag, bq_ag, ws + o_Kag, ws + o_Qa);
    k_transpose<<<dim3(24, 12), dim3(32, 8), 0, stream>>>(Wk_hf, ws + o_WkT);
    k_tcastT<<<dim3(6, 12, 1), 256, 0, stream>>>(Wq_lf, WqT2, nullptr,
                                                 KC, KC2, 0, 0, 0);
    k_tcastT<<<dim3(6, 6, 1), 256, 0, stream>>>(Wv_hf, WvT2, nullptr,
                                                 KC, KC, 0, 0, 0);
    k_kabc<<<dim3(KB), 256, 0, stream>>>(ws + o_Kag, ws + o_Qa, wa, bk_hf, wb, bb,
                                         KA, ws + o_cB);
    k_build_F<<<dim3(96, 8), 128, 0, stream>>>(ws + o_WkT, ws + o_Qa, wb, Fbf);

    // V = attn @ Wv + bv  (also emits Abf; overwrites the HL temps — safe, agproj2 done)
    k_vproj2<<<dim3(KN/64, KB), 512, vp_lds, stream>>>(attn, WvT2, bv_hf, Abf, Vt2);

    const int g_per = KB * NCH;   // 128
    k_flash3<<<dim3(KH * g_per), 512, fl_lds, stream>>>(
        Abf, Vt2, Fbf, ws + o_cB, ws + o_Vp, ws + o_lp, NCH, KN / NCH, g_per);
    k_combine4<<<dim3(KH, KB, 4), 384, 0, stream>>>(
        ws + o_Vp, ws + o_lp, Wproj, Mt2);
    // Q = x @ Wq_lf + bq -> QAf (overlays dead flash-region)
    k_qkproj<<<dim3(KN/64, KB, 2), 512, qp_lds, stream>>>(x, WqT2, bq_lf, QAf);
    k_out5<<<dim3(KN/64, KB), 512, ko_lds, stream>>>(
        QAf, KA, ba, Mt2, bproj, out);
}